// Round 7
// baseline (522.995 us; speedup 1.0000x reference)
//
#include <hip/hip_runtime.h>
#include <math.h>

// Shapes (fixed): B=4, C=256, H=W=64, N=4096, 4C=1024, c8=32, r=16.

typedef float f32x4 __attribute__((ext_vector_type(4)));
typedef short s16x8 __attribute__((ext_vector_type(8)));
union FRAG { uint4 u; s16x8 s; };

__device__ __forceinline__ unsigned short f2bf(float f) {
    union { float f; unsigned int u; } v; v.f = f;
    unsigned int r = v.u + 0x7FFFu + ((v.u >> 16) & 1u);
    return (unsigned short)(r >> 16);
}

// ---------------------------------------------------------------------------
// K1/K5: per-(b,c) plane -> block-mean pyramid (+ feats in mode 0, x2 in mode 1)
// ---------------------------------------------------------------------------
__global__ __launch_bounds__(256) void k_pyramid(
    const float* __restrict__ xin, const float* __restrict__ gch,
    const float* __restrict__ spg, float* __restrict__ x2out,
    float* __restrict__ bm2, float* __restrict__ bm4, float* __restrict__ bm8,
    float* __restrict__ featA, float* __restrict__ fm1, float* __restrict__ fm2,
    float* __restrict__ fm4, float* __restrict__ fm8, int mode)
{
    __shared__ float sx[4096];
    __shared__ float s2[1024];
    __shared__ float s4[256];
    __shared__ float wred[4][8];
    const int bc = blockIdx.x;
    const int b = bc >> 8;
    const int t = threadIdx.x;
    const float* xp = xin + (size_t)bc * 4096;
    float gc = 1.f;
    if (mode == 1) gc = gch[bc];
    float sum = 0.f, mx = -1e30f;
    for (int r = 0; r < 4; r++) {
        int i4 = t + 256 * r;
        float4 v = ((const float4*)xp)[i4];
        if (mode == 1) {
            float4 sg = ((const float4*)(spg + (size_t)b * 4096))[i4];
            v.x *= gc * sg.x; v.y *= gc * sg.y; v.z *= gc * sg.z; v.w *= gc * sg.w;
            ((float4*)(x2out + (size_t)bc * 4096))[i4] = v;
        } else {
            sum += v.x + v.y + v.z + v.w;
            mx = fmaxf(mx, fmaxf(fmaxf(v.x, v.y), fmaxf(v.z, v.w)));
        }
        ((float4*)sx)[i4] = v;
    }
    __syncthreads();
    float mx2 = -1e30f;
    for (int r = 0; r < 4; r++) {
        int i = t + 256 * r;
        int r2 = i >> 5, c2 = i & 31;
        int p0 = 128 * r2 + 2 * c2;
        float v = 0.25f * (sx[p0] + sx[p0 + 1] + sx[p0 + 64] + sx[p0 + 65]);
        s2[i] = v;
        bm2[(size_t)bc * 1024 + i] = v;
        mx2 = fmaxf(mx2, v);
    }
    __syncthreads();
    float mx4;
    {
        int r4 = t >> 4, c4 = t & 15;
        int p0 = 64 * r4 + 2 * c4;
        float v = 0.25f * (s2[p0] + s2[p0 + 1] + s2[p0 + 32] + s2[p0 + 33]);
        s4[t] = v;
        bm4[(size_t)bc * 256 + t] = v;
        mx4 = v;
    }
    __syncthreads();
    float mx8 = -1e30f;
    if (t < 64) {
        int r8 = t >> 3, c8 = t & 7;
        int p0 = 32 * r8 + 2 * c8;
        float v = 0.25f * (s4[p0] + s4[p0 + 1] + s4[p0 + 16] + s4[p0 + 17]);
        bm8[(size_t)bc * 64 + t] = v;
        mx8 = v;
    }
    if (mode == 0) {
        float vs = sum, v1 = mx, v2 = mx2, v4 = mx4, v8 = mx8;
        #pragma unroll
        for (int o = 1; o < 64; o <<= 1) {
            vs += __shfl_xor(vs, o);
            v1 = fmaxf(v1, __shfl_xor(v1, o));
            v2 = fmaxf(v2, __shfl_xor(v2, o));
            v4 = fmaxf(v4, __shfl_xor(v4, o));
            v8 = fmaxf(v8, __shfl_xor(v8, o));
        }
        if ((t & 63) == 0) {
            int wd = t >> 6;
            wred[wd][0] = vs; wred[wd][1] = v1; wred[wd][2] = v2;
            wred[wd][3] = v4; wred[wd][4] = v8;
        }
        __syncthreads();
        if (t == 0) featA[bc] = (wred[0][0] + wred[1][0] + wred[2][0] + wred[3][0]) * (1.f / 4096.f);
        else if (t == 1) fm1[bc] = fmaxf(fmaxf(wred[0][1], wred[1][1]), fmaxf(wred[2][1], wred[3][1]));
        else if (t == 2) fm2[bc] = fmaxf(fmaxf(wred[0][2], wred[1][2]), fmaxf(wred[2][2], wred[3][2]));
        else if (t == 3) fm4[bc] = fmaxf(fmaxf(wred[0][3], wred[1][3]), fmaxf(wred[2][3], wred[3][3]));
        else if (t == 4) fm8[bc] = fmaxf(fmaxf(wred[0][4], wred[1][4]), fmaxf(wred[2][4], wred[3][4]));
    }
}

// ---------------------------------------------------------------------------
// K2: channel-gate MLP
// ---------------------------------------------------------------------------
__global__ __launch_bounds__(256) void k2_gate(
    const float* __restrict__ featA, const float* __restrict__ fm1,
    const float* __restrict__ fm2, const float* __restrict__ fm4, const float* __restrict__ fm8,
    const float* __restrict__ W1, const float* __restrict__ b1,
    const float* __restrict__ W2, const float* __restrict__ b2,
    float* __restrict__ g)
{
    __shared__ float sf[5][256];
    __shared__ float sh[5][16];
    __shared__ float hs[16];
    const int b = blockIdx.x, t = threadIdx.x;
    sf[0][t] = featA[b * 256 + t];
    sf[1][t] = fm1[b * 256 + t];
    sf[2][t] = fm2[b * 256 + t];
    sf[3][t] = fm4[b * 256 + t];
    sf[4][t] = fm8[b * 256 + t];
    __syncthreads();
    if (t < 80) {
        int f = t / 16, j = t % 16;
        float a = b1[j];
        for (int c = 0; c < 256; c++) a += sf[f][c] * W1[c * 16 + j];
        sh[f][j] = fmaxf(a, 0.f);
    }
    __syncthreads();
    if (t < 16) hs[t] = 4.f * sh[0][t] + sh[1][t] + sh[2][t] + sh[3][t] + sh[4][t];
    __syncthreads();
    float a = 8.f * b2[t];
    for (int j = 0; j < 16; j++) a += hs[j] * W2[j * 256 + t];
    g[b * 256 + t] = 1.f / (1.f + __expf(-a));
}

// ---------------------------------------------------------------------------
// K3: spatial-gate input. Grid 256: block = (b, 64-pixel chunk); 4 waves
// split the 256 channels; LDS cross-wave reduce.
// ---------------------------------------------------------------------------
__global__ __launch_bounds__(256) void k3_comp(
    const float* __restrict__ x, const float* __restrict__ bm2,
    const float* __restrict__ bm4, const float* __restrict__ bm8,
    const float* __restrict__ g, float* __restrict__ comp)
{
    __shared__ float sg[256];
    __shared__ float rmx[4][64];
    __shared__ float rsm[4][64];
    const int b = blockIdx.x >> 6;
    const int pix = ((blockIdx.x & 63) << 6) + (threadIdx.x & 63);
    const int wid = threadIdx.x >> 6;
    const int c0 = wid << 6;
    sg[threadIdx.x] = g[(b << 8) + threadIdx.x];
    __syncthreads();
    const int h = pix >> 6, w = pix & 63;
    const int i2 = ((h >> 1) << 5) + (w >> 1);
    const int i4 = ((h >> 2) << 4) + (w >> 2);
    const int i8 = ((h >> 3) << 3) + (w >> 3);
    const float* xb = x + ((size_t)b << 8) * 4096;
    const float* p2 = bm2 + ((size_t)b << 8) * 1024;
    const float* p4 = bm4 + ((size_t)b << 8) * 256;
    const float* p8 = bm8 + ((size_t)b << 8) * 64;
    float mx = -1e30f, sm = 0.f;
    for (int c = c0; c < c0 + 64; c++) {
        float gc = sg[c];
        float xv = xb[(size_t)c * 4096 + pix] * gc;
        float v2 = p2[c * 1024 + i2] * gc;
        float v4 = p4[c * 256 + i4] * gc;
        float v8 = p8[c * 64 + i8] * gc;
        mx = fmaxf(fmaxf(mx, xv), fmaxf(fmaxf(v2, v4), v8));
        sm += xv + v2 + v4 + v8;
    }
    rmx[wid][threadIdx.x & 63] = mx;
    rsm[wid][threadIdx.x & 63] = sm;
    __syncthreads();
    if (wid == 0) {
        int l = threadIdx.x;
        float m = fmaxf(fmaxf(rmx[0][l], rmx[1][l]), fmaxf(rmx[2][l], rmx[3][l]));
        float s = rsm[0][l] + rsm[1][l] + rsm[2][l] + rsm[3][l];
        comp[((size_t)b * 2) * 4096 + pix] = m;
        comp[((size_t)b * 2 + 1) * 4096 + pix] = s * (1.f / 1024.f);
    }
}

// ---------------------------------------------------------------------------
// K4: 7x7 conv (2->1, pad 3, no bias) + BN(eval) + sigmoid. Grid 256 x 64thr.
// ---------------------------------------------------------------------------
__global__ __launch_bounds__(64) void k4_spgate(
    const float* __restrict__ comp, const float* __restrict__ Wsp,
    const float* __restrict__ bn_g, const float* __restrict__ bn_b,
    const float* __restrict__ bn_m, const float* __restrict__ bn_v,
    float* __restrict__ spg)
{
    __shared__ float w[98];
    const int t = threadIdx.x;
    for (int i = t; i < 98; i += 64) w[i] = Wsp[i];
    __syncthreads();
    const int b = blockIdx.x >> 6;
    const int pix = ((blockIdx.x & 63) << 6) + t;
    const int h = pix >> 6, wx = pix & 63;
    const float* c0 = comp + (size_t)b * 2 * 4096;
    float acc = 0.f;
    for (int ci = 0; ci < 2; ci++)
        for (int kh = 0; kh < 7; kh++) {
            int hh = h + kh - 3;
            if (hh < 0 || hh >= 64) continue;
            for (int kw = 0; kw < 7; kw++) {
                int wwp = wx + kw - 3;
                if (wwp < 0 || wwp >= 64) continue;
                acc += c0[ci * 4096 + hh * 64 + wwp] * w[ci * 49 + kh * 7 + kw];
            }
        }
    float sc = rsqrtf(bn_v[0] + 1e-5f) * bn_g[0];
    float sp = (acc - bn_m[0]) * sc + bn_b[0];
    spg[b * 4096 + pix] = 1.f / (1.f + __expf(-sp));
}

// ---------------------------------------------------------------------------
// K_WCAST: bf16 copy of W[:,768:1024] rows (q|k|v order) -> WB[320][256]
// ---------------------------------------------------------------------------
__global__ __launch_bounds__(256) void k_wcast(
    const float* __restrict__ Wq, const float* __restrict__ Wk, const float* __restrict__ Wv,
    unsigned short* __restrict__ WB)
{
    const int o = blockIdx.x;
    const int t = threadIdx.x;
    const float* row = (o < 32) ? (Wq + (size_t)o * 1024)
                      : (o < 64) ? (Wk + (size_t)(o - 32) * 1024)
                                 : (Wv + (size_t)(o - 64) * 1024);
    WB[o * 256 + t] = f2bf(row[768 + t]);
}

// ---------------------------------------------------------------------------
// K_X2T: x2 fp32 [b][256 c][4096 n] -> x2T bf16 [b][4096 n][256 c]
// ---------------------------------------------------------------------------
__global__ __launch_bounds__(256) void k_x2t(
    const float* __restrict__ x2, unsigned short* __restrict__ x2T)
{
    __shared__ unsigned short T[64][72];
    const int b = blockIdx.z;
    const int cb = blockIdx.y * 64;
    const int nb = blockIdx.x * 64;
    const int t = threadIdx.x;
    #pragma unroll
    for (int r = 0; r < 16; r++) {
        int cl = (t >> 6) + 4 * r;
        int nl = t & 63;
        float v = x2[((size_t)(b * 256 + cb + cl)) * 4096 + nb + nl];
        T[nl][cl] = f2bf(v);
    }
    __syncthreads();
    #pragma unroll
    for (int pass = 0; pass < 4; pass++) {
        int nl = (t >> 4) + 16 * pass;
        int c4 = (t & 15) * 4;
        uint2 pk;
        pk.x = (unsigned)T[nl][c4] | ((unsigned)T[nl][c4 + 1] << 16);
        pk.y = (unsigned)T[nl][c4 + 2] | ((unsigned)T[nl][c4 + 3] << 16);
        *(uint2*)(x2T + ((size_t)(b * 4096 + nb + nl)) * 256 + cb + c4) = pk;
    }
}

// ---------------------------------------------------------------------------
// K6: fp32 projection GEMM for low-res P2/P4/P8 passes only.
// ---------------------------------------------------------------------------
__global__ __launch_bounds__(256) void k6_gemm(
    const float* __restrict__ Wq, const float* __restrict__ Wk, const float* __restrict__ Wv,
    int col_off, const float* __restrict__ src, int ns,
    float* __restrict__ outp)
{
    __shared__ float At[32][68];
    __shared__ float Bt[32][64];
    const int b = blockIdx.z;
    const int o_base = blockIdx.y * 64;
    const int n_base = blockIdx.x * 64;
    const int t = threadIdx.x;
    const int tn = t >> 4, tm = t & 15;
    const int lk = t & 31, lo8 = t >> 5;
    const int ln = t & 63, lk4 = t >> 6;
    float acc[4][4];
    #pragma unroll
    for (int i = 0; i < 4; i++)
        #pragma unroll
        for (int j = 0; j < 4; j++) acc[i][j] = 0.f;
    for (int k0 = 0; k0 < 256; k0 += 32) {
        __syncthreads();
        #pragma unroll
        for (int r = 0; r < 8; r++) {
            int o = o_base + lo8 + 8 * r;
            const float* wrow = (o < 32) ? (Wq + (size_t)o * 1024)
                              : (o < 64) ? (Wk + (size_t)(o - 32) * 1024)
                                         : (Wv + (size_t)(o - 64) * 1024);
            At[lk][lo8 + 8 * r] = wrow[col_off + k0 + lk];
        }
        #pragma unroll
        for (int r = 0; r < 8; r++)
            Bt[lk4 + 4 * r][ln] = src[((size_t)b * 256 + k0 + lk4 + 4 * r) * ns + n_base + ln];
        __syncthreads();
        #pragma unroll
        for (int kk = 0; kk < 32; kk++) {
            float4 a = *(const float4*)&At[kk][4 * tn];
            float4 bb = *(const float4*)&Bt[kk][4 * tm];
            acc[0][0] += a.x * bb.x; acc[0][1] += a.x * bb.y; acc[0][2] += a.x * bb.z; acc[0][3] += a.x * bb.w;
            acc[1][0] += a.y * bb.x; acc[1][1] += a.y * bb.y; acc[1][2] += a.y * bb.z; acc[1][3] += a.y * bb.w;
            acc[2][0] += a.z * bb.x; acc[2][1] += a.z * bb.y; acc[2][2] += a.z * bb.z; acc[2][3] += a.z * bb.w;
            acc[3][0] += a.w * bb.x; acc[3][1] += a.w * bb.y; acc[3][2] += a.w * bb.z; acc[3][3] += a.w * bb.w;
        }
    }
    #pragma unroll
    for (int i = 0; i < 4; i++)
        #pragma unroll
        for (int j = 0; j < 4; j++)
            outp[((size_t)b * 320 + o_base + 4 * tn + i) * ns + n_base + 4 * tm + j] = acc[i][j];
}

// ---------------------------------------------------------------------------
// K6M: full-res projection via bf16 MFMA (unchanged).
// ---------------------------------------------------------------------------
__global__ __launch_bounds__(256) void k6m(
    const unsigned short* __restrict__ WB, const unsigned short* __restrict__ x2T,
    const float* __restrict__ bq, const float* __restrict__ bk, const float* __restrict__ bv,
    const float* __restrict__ P2, const float* __restrict__ P4, const float* __restrict__ P8,
    unsigned short* __restrict__ qT, unsigned short* __restrict__ kT,
    unsigned short* __restrict__ vB)
{
    const int b = blockIdx.z;
    const int obase = blockIdx.y * 64;
    const int nb = blockIdx.x * 128;
    const int t = threadIdx.x;
    const int w_ = t >> 6, lane = t & 63;
    const int quad = lane >> 4, l16 = lane & 15;
    const int nbase = nb + 32 * w_;
    f32x4 acc[4][2];
    #pragma unroll
    for (int ot = 0; ot < 4; ot++)
        #pragma unroll
        for (int nt = 0; nt < 2; nt++) { acc[ot][nt][0] = 0.f; acc[ot][nt][1] = 0.f; acc[ot][nt][2] = 0.f; acc[ot][nt][3] = 0.f; }
    const unsigned short* xb = x2T + ((size_t)b * 4096 + nbase) * 256;
    for (int k0 = 0; k0 < 256; k0 += 32) {
        FRAG af[4], bf[2];
        #pragma unroll
        for (int ot = 0; ot < 4; ot++)
            af[ot].u = *(const uint4*)(WB + (size_t)(obase + 16 * ot + l16) * 256 + k0 + quad * 8);
        #pragma unroll
        for (int nt = 0; nt < 2; nt++)
            bf[nt].u = *(const uint4*)(xb + (size_t)(16 * nt + l16) * 256 + k0 + quad * 8);
        #pragma unroll
        for (int ot = 0; ot < 4; ot++)
            #pragma unroll
            for (int nt = 0; nt < 2; nt++)
                acc[ot][nt] = __builtin_amdgcn_mfma_f32_16x16x32_bf16(af[ot].s, bf[nt].s, acc[ot][nt], 0, 0, 0);
    }
    #pragma unroll
    for (int ot = 0; ot < 4; ot++) {
        #pragma unroll
        for (int nt = 0; nt < 2; nt++) {
            int n = nbase + 16 * nt + l16;
            int h = n >> 6, wx = n & 63;
            int i2 = ((h >> 1) << 5) + (wx >> 1);
            int i4 = ((h >> 2) << 4) + (wx >> 2);
            int i8 = ((h >> 3) << 3) + (wx >> 3);
            float vals[4];
            #pragma unroll
            for (int r = 0; r < 4; r++) {
                int o = obase + 16 * ot + 4 * quad + r;
                float bias = (o < 32) ? bq[o] : (o < 64) ? bk[o - 32] : bv[o - 64];
                size_t ro = (size_t)b * 320 + o;
                vals[r] = acc[ot][nt][r] + bias
                        + P2[ro * 1024 + i2] + P4[ro * 256 + i4] + P8[ro * 64 + i8];
            }
            int o0 = obase + 16 * ot + 4 * quad;
            if (o0 < 64) {
                uint2 pk;
                pk.x = (unsigned)f2bf(vals[0]) | ((unsigned)f2bf(vals[1]) << 16);
                pk.y = (unsigned)f2bf(vals[2]) | ((unsigned)f2bf(vals[3]) << 16);
                if (o0 < 32)
                    *(uint2*)(qT + ((size_t)(b * 4096 + n)) * 32 + o0) = pk;
                else
                    *(uint2*)(kT + ((size_t)(b * 4096 + n)) * 32 + (o0 - 32)) = pk;
            } else {
                #pragma unroll
                for (int r = 0; r < 4; r++)
                    vB[((size_t)(b * 256) + o0 - 64 + r) * 4096 + n] = f2bf(vals[r]);
            }
        }
    }
}

// ---------------------------------------------------------------------------
// K7A: softmax stats pass. Block = (b, 64q), 1024 thr / 16 waves =
// 4 q-groups x 4 key-quarters. Online (m,l) kept FULLY per-lane in the loop
// (each lane tracks only its own quad's rows -> no shfl in loop). End:
// cross-quad shfl combine, cross-wave LDS combine (1 barrier), write
// m[b][n] and 1/l[b][n].
// ---------------------------------------------------------------------------
__global__ __launch_bounds__(1024, 4) void k7a_stats(
    const unsigned short* __restrict__ qT, const unsigned short* __restrict__ kT,
    float* __restrict__ mout, float* __restrict__ ilout)
{
    __shared__ float sm[4][4][16], sl[4][4][16];   // [g][s][l16]
    const int b = blockIdx.x >> 6;
    const int qbase = (blockIdx.x & 63) << 6;
    const int t = threadIdx.x;
    const int wid = t >> 6, lane = t & 63;
    const int g_ = wid >> 2, s_ = wid & 3;
    const int quad = lane >> 4, l16 = lane & 15;

    FRAG qf;
    qf.u = *(const uint4*)(qT + ((size_t)(b * 4096 + qbase + 16 * g_ + l16)) * 32 + quad * 8);
    const unsigned short* kTb = kT + (size_t)b * 4096 * 32;

    float m_run = -1e30f, l_run = 0.f;
    for (int j = 0; j < 16; j++) {
        const int mo = (s_ << 10) + (j << 6);
        f32x4 e[4];
        #pragma unroll
        for (int mt = 0; mt < 4; mt++) {
            FRAG kf;
            kf.u = *(const uint4*)(kTb + (size_t)(mo + 16 * mt + l16) * 32 + quad * 8);
            f32x4 z; z[0] = 0.f; z[1] = 0.f; z[2] = 0.f; z[3] = 0.f;
            e[mt] = __builtin_amdgcn_mfma_f32_16x16x32_bf16(kf.s, qf.s, z, 0, 0, 0);
        }
        float pm = e[0][0];
        #pragma unroll
        for (int mt = 0; mt < 4; mt++)
            #pragma unroll
            for (int r = 0; r < 4; r++) pm = fmaxf(pm, e[mt][r]);
        float mnew = fmaxf(m_run, pm);
        float al = __expf(m_run - mnew);
        float ps = 0.f;
        #pragma unroll
        for (int mt = 0; mt < 4; mt++)
            #pragma unroll
            for (int r = 0; r < 4; r++) ps += __expf(e[mt][r] - mnew);
        l_run = l_run * al + ps;
        m_run = mnew;
    }
    // cross-quad combine (lanes l16, l16+16, l16+32, l16+48 share n)
    #pragma unroll
    for (int o = 16; o < 64; o <<= 1) {
        float mo_ = __shfl_xor(m_run, o);
        float lo_ = __shfl_xor(l_run, o);
        float m2 = fmaxf(m_run, mo_);
        l_run = l_run * __expf(m_run - m2) + lo_ * __expf(mo_ - m2);
        m_run = m2;
    }
    if (quad == 0) { sm[g_][s_][l16] = m_run; sl[g_][s_][l16] = l_run; }
    __syncthreads();
    if (t < 64) {
        int g = t >> 4, l = t & 15;
        float m0 = sm[g][0][l], m1 = sm[g][1][l], m2 = sm[g][2][l], m3 = sm[g][3][l];
        float mx = fmaxf(fmaxf(m0, m1), fmaxf(m2, m3));
        float l_ = sl[g][0][l] * __expf(m0 - mx) + sl[g][1][l] * __expf(m1 - mx)
                 + sl[g][2][l] * __expf(m2 - mx) + sl[g][3][l] * __expf(m3 - mx);
        int n = qbase + 16 * g + l;
        mout[b * 4096 + n] = mx;
        ilout[b * 4096 + n] = 1.f / l_;
    }
}

// ---------------------------------------------------------------------------
// K7B: PV pass. Q-split, barrier-free, ZERO loop-carried state (m is a
// loop-invariant per-lane scalar from k7a). Iterations fully independent ->
// hardware overlaps iter i+1 QK/exp with iter i PV. Block = (b, 64q),
// 16 waves = 4 q-groups x 4 c-stripe waves; wave-private PL.
// ---------------------------------------------------------------------------
__global__ __launch_bounds__(1024, 4) void k7b_attn(
    const unsigned short* __restrict__ qT, const unsigned short* __restrict__ kT,
    const unsigned short* __restrict__ vB, const float* __restrict__ mstat,
    const float* __restrict__ ilstat, const float* __restrict__ x2,
    const float* __restrict__ gamma, float* __restrict__ outp)
{
    __shared__ unsigned short PL[16][16][72];   // [wave][n local][m], wave-private
    const int b = blockIdx.x >> 6;
    const int qbase = (blockIdx.x & 63) << 6;
    const int t = threadIdx.x;
    const int wid = t >> 6, lane = t & 63;
    const int g_ = wid >> 2, w_ = wid & 3;
    const int quad = lane >> 4, l16 = lane & 15;
    const int n = qbase + 16 * g_ + l16;

    FRAG qf;
    qf.u = *(const uint4*)(qT + ((size_t)(b * 4096 + n)) * 32 + quad * 8);
    const float mN = mstat[b * 4096 + n];
    const float ilN = ilstat[b * 4096 + n];

    f32x4 acc[4];
    #pragma unroll
    for (int ct = 0; ct < 4; ct++) { acc[ct][0] = 0.f; acc[ct][1] = 0.f; acc[ct][2] = 0.f; acc[ct][3] = 0.f; }
    const unsigned short* kTb = kT + (size_t)b * 4096 * 32;
    const unsigned short* vBb = vB + (size_t)b * 256 * 4096;

    for (int mo = 0; mo < 4096; mo += 64) {
        // --- QK^T ---
        f32x4 e[4];
        #pragma unroll
        for (int mt = 0; mt < 4; mt++) {
            FRAG kf;
            kf.u = *(const uint4*)(kTb + (size_t)(mo + 16 * mt + l16) * 32 + quad * 8);
            f32x4 z; z[0] = 0.f; z[1] = 0.f; z[2] = 0.f; z[3] = 0.f;
            e[mt] = __builtin_amdgcn_mfma_f32_16x16x32_bf16(kf.s, qf.s, z, 0, 0, 0);
        }
        // --- P = exp(e - m), pack, wave-private LDS ---
        #pragma unroll
        for (int mt = 0; mt < 4; mt++) {
            union { float f; unsigned int u; } p0, p1, p2, p3;
            p0.f = __expf(e[mt][0] - mN);
            p1.f = __expf(e[mt][1] - mN);
            p2.f = __expf(e[mt][2] - mN);
            p3.f = __expf(e[mt][3] - mN);
            uint2 pk;
            pk.x = __builtin_amdgcn_perm(p1.u, p0.u, 0x07060302u);
            pk.y = __builtin_amdgcn_perm(p3.u, p2.u, 0x07060302u);
            *(uint2*)&PL[wid][l16][16 * mt + 4 * quad] = pk;
        }
        // --- PV: O[c][n] += V[c][m] * P^T[m][n], c-stripe [64w_, 64w_+64) ---
        #pragma unroll
        for (int kh = 0; kh < 2; kh++) {
            FRAG av[4], bp;
            bp.u = *(const uint4*)&PL[wid][l16][32 * kh + quad * 8];
            #pragma unroll
            for (int ct = 0; ct < 4; ct++)
                av[ct].u = *(const uint4*)(vBb + (size_t)(64 * w_ + 16 * ct + l16) * 4096
                                           + mo + 32 * kh + quad * 8);
            #pragma unroll
            for (int ct = 0; ct < 4; ct++)
                acc[ct] = __builtin_amdgcn_mfma_f32_16x16x32_bf16(av[ct].s, bp.s, acc[ct], 0, 0, 0);
        }
    }
    // --- epilogue: pure per-lane scale; direct stores ---
    const float gm = gamma[0];
    const float sc = gm * ilN;
    #pragma unroll
    for (int ct = 0; ct < 4; ct++) {
        #pragma unroll
        for (int r = 0; r < 4; r++) {
            int c = 64 * w_ + 16 * ct + 4 * quad + r;
            size_t idx = ((size_t)b * 256 + c) * 4096 + n;
            outp[idx] = sc * acc[ct][r] + x2[idx];
        }
    }
}

// ---------------------------------------------------------------------------
extern "C" void kernel_launch(void* const* d_in, const int* in_sizes, int n_in,
                              void* d_out, int out_size, void* d_ws, size_t ws_size,
                              hipStream_t stream) {
    (void)in_sizes; (void)n_in; (void)out_size; (void)ws_size;
    const float* x    = (const float*)d_in[0];
    const float* W1   = (const float*)d_in[1];
    const float* b1   = (const float*)d_in[2];
    const float* W2   = (const float*)d_in[3];
    const float* b2   = (const float*)d_in[4];
    const float* Wq   = (const float*)d_in[5];
    const float* bq   = (const float*)d_in[6];
    const float* Wk   = (const float*)d_in[7];
    const float* bk   = (const float*)d_in[8];
    const float* Wv   = (const float*)d_in[9];
    const float* bv   = (const float*)d_in[10];
    const float* gam  = (const float*)d_in[11];
    const float* Wsp  = (const float*)d_in[12];
    const float* bn_g = (const float*)d_in[13];
    const float* bn_b = (const float*)d_in[14];
    const float* bn_m = (const float*)d_in[15];
    const float* bn_v = (const float*)d_in[16];

    float* ws = (float*)d_ws;
    float* bm2   = ws; ws += (size_t)4 * 256 * 1024;
    float* bm4   = ws; ws += (size_t)4 * 256 * 256;
    float* bm8   = ws; ws += (size_t)4 * 256 * 64;
    float* featA = ws; ws += 1024;
    float* fm1   = ws; ws += 1024;
    float* fm2   = ws; ws += 1024;
    float* fm4   = ws; ws += 1024;
    float* fm8   = ws; ws += 1024;
    float* g     = ws; ws += 1024;
    float* comp  = ws; ws += (size_t)4 * 2 * 4096;
    float* spg   = ws; ws += (size_t)4 * 4096;
    float* x2    = ws; ws += (size_t)4 * 256 * 4096;
    float* bm2b  = ws; ws += (size_t)4 * 256 * 1024;
    float* bm4b  = ws; ws += (size_t)4 * 256 * 256;
    float* bm8b  = ws; ws += (size_t)4 * 256 * 64;
    float* P2    = ws; ws += (size_t)4 * 320 * 1024;
    float* P4    = ws; ws += (size_t)4 * 320 * 256;
    float* P8    = ws; ws += (size_t)4 * 320 * 64;
    float* mstat = ws; ws += (size_t)4 * 4096;
    float* ilstat= ws; ws += (size_t)4 * 4096;
    unsigned short* qT  = (unsigned short*)ws; ws += (size_t)4 * 4096 * 32 / 2;
    unsigned short* kT  = (unsigned short*)ws; ws += (size_t)4 * 4096 * 32 / 2;
    unsigned short* vB  = (unsigned short*)ws; ws += (size_t)4 * 256 * 4096 / 2;
    unsigned short* x2T = (unsigned short*)ws; ws += (size_t)4 * 4096 * 256 / 2;
    unsigned short* WB  = (unsigned short*)ws; ws += (size_t)320 * 256 / 2;

    // Weight cast (no deps)
    k_wcast<<<320, 256, 0, stream>>>(Wq, Wk, Wv, WB);
    // Stage 1: channel gate
    k_pyramid<<<1024, 256, 0, stream>>>(x, nullptr, nullptr, nullptr,
                                        bm2, bm4, bm8, featA, fm1, fm2, fm4, fm8, 0);
    k2_gate<<<4, 256, 0, stream>>>(featA, fm1, fm2, fm4, fm8, W1, b1, W2, b2, g);
    // Stage 2: spatial gate
    k3_comp<<<256, 256, 0, stream>>>(x, bm2, bm4, bm8, g, comp);
    k4_spgate<<<256, 64, 0, stream>>>(comp, Wsp, bn_g, bn_b, bn_m, bn_v, spg);
    k_pyramid<<<1024, 256, 0, stream>>>(x, g, spg, x2,
                                        bm2b, bm4b, bm8b,
                                        nullptr, nullptr, nullptr, nullptr, nullptr, 1);
    // x2 -> bf16 transposed [n][c]
    k_x2t<<<dim3(64, 4, 4), 256, 0, stream>>>(x2, x2T);
    // Stage 3: q/k/v projections, multiscale-decomposed
    k6_gemm<<<dim3(16, 5, 4), 256, 0, stream>>>(Wq, Wk, Wv, 0,   bm2b, 1024, P2);
    k6_gemm<<<dim3(4, 5, 4), 256, 0, stream>>>(Wq, Wk, Wv, 256, bm4b, 256,  P4);
    k6_gemm<<<dim3(1, 5, 4), 256, 0, stream>>>(Wq, Wk, Wv, 512, bm8b, 64,   P8);
    k6m<<<dim3(32, 5, 4), 256, 0, stream>>>(WB, x2T, bq, bk, bv, P2, P4, P8, qT, kT, vB);
    // Two-pass attention: stats, then barrier-free dependency-free PV
    k7a_stats<<<256, 1024, 0, stream>>>(qT, kT, mstat, ilstat);
    k7b_attn<<<256, 1024, 0, stream>>>(qT, kT, vB, mstat, ilstat, x2, gam, (float*)d_out);
}

// Round 8
// 348.390 us; speedup vs baseline: 1.5012x; 1.5012x over previous
//
#include <hip/hip_runtime.h>
#include <math.h>

// Shapes (fixed): B=4, C=256, H=W=64, N=4096, 4C=1024, c8=32, r=16.

typedef float f32x4 __attribute__((ext_vector_type(4)));
typedef short s16x8 __attribute__((ext_vector_type(8)));
union FRAG { uint4 u; s16x8 s; };

__device__ __forceinline__ unsigned short f2bf(float f) {
    union { float f; unsigned int u; } v; v.f = f;
    unsigned int r = v.u + 0x7FFFu + ((v.u >> 16) & 1u);
    return (unsigned short)(r >> 16);
}

// ---------------------------------------------------------------------------
// K1/K5: per-(b,c) plane -> block-mean pyramid (+ feats in mode 0, x2 in mode 1)
// ---------------------------------------------------------------------------
__global__ __launch_bounds__(256) void k_pyramid(
    const float* __restrict__ xin, const float* __restrict__ gch,
    const float* __restrict__ spg, float* __restrict__ x2out,
    float* __restrict__ bm2, float* __restrict__ bm4, float* __restrict__ bm8,
    float* __restrict__ featA, float* __restrict__ fm1, float* __restrict__ fm2,
    float* __restrict__ fm4, float* __restrict__ fm8, int mode)
{
    __shared__ float sx[4096];
    __shared__ float s2[1024];
    __shared__ float s4[256];
    __shared__ float wred[4][8];
    const int bc = blockIdx.x;
    const int b = bc >> 8;
    const int t = threadIdx.x;
    const float* xp = xin + (size_t)bc * 4096;
    float gc = 1.f;
    if (mode == 1) gc = gch[bc];
    float sum = 0.f, mx = -1e30f;
    for (int r = 0; r < 4; r++) {
        int i4 = t + 256 * r;
        float4 v = ((const float4*)xp)[i4];
        if (mode == 1) {
            float4 sg = ((const float4*)(spg + (size_t)b * 4096))[i4];
            v.x *= gc * sg.x; v.y *= gc * sg.y; v.z *= gc * sg.z; v.w *= gc * sg.w;
            ((float4*)(x2out + (size_t)bc * 4096))[i4] = v;
        } else {
            sum += v.x + v.y + v.z + v.w;
            mx = fmaxf(mx, fmaxf(fmaxf(v.x, v.y), fmaxf(v.z, v.w)));
        }
        ((float4*)sx)[i4] = v;
    }
    __syncthreads();
    float mx2 = -1e30f;
    for (int r = 0; r < 4; r++) {
        int i = t + 256 * r;
        int r2 = i >> 5, c2 = i & 31;
        int p0 = 128 * r2 + 2 * c2;
        float v = 0.25f * (sx[p0] + sx[p0 + 1] + sx[p0 + 64] + sx[p0 + 65]);
        s2[i] = v;
        bm2[(size_t)bc * 1024 + i] = v;
        mx2 = fmaxf(mx2, v);
    }
    __syncthreads();
    float mx4;
    {
        int r4 = t >> 4, c4 = t & 15;
        int p0 = 64 * r4 + 2 * c4;
        float v = 0.25f * (s2[p0] + s2[p0 + 1] + s2[p0 + 32] + s2[p0 + 33]);
        s4[t] = v;
        bm4[(size_t)bc * 256 + t] = v;
        mx4 = v;
    }
    __syncthreads();
    float mx8 = -1e30f;
    if (t < 64) {
        int r8 = t >> 3, c8 = t & 7;
        int p0 = 32 * r8 + 2 * c8;
        float v = 0.25f * (s4[p0] + s4[p0 + 1] + s4[p0 + 16] + s4[p0 + 17]);
        bm8[(size_t)bc * 64 + t] = v;
        mx8 = v;
    }
    if (mode == 0) {
        float vs = sum, v1 = mx, v2 = mx2, v4 = mx4, v8 = mx8;
        #pragma unroll
        for (int o = 1; o < 64; o <<= 1) {
            vs += __shfl_xor(vs, o);
            v1 = fmaxf(v1, __shfl_xor(v1, o));
            v2 = fmaxf(v2, __shfl_xor(v2, o));
            v4 = fmaxf(v4, __shfl_xor(v4, o));
            v8 = fmaxf(v8, __shfl_xor(v8, o));
        }
        if ((t & 63) == 0) {
            int wd = t >> 6;
            wred[wd][0] = vs; wred[wd][1] = v1; wred[wd][2] = v2;
            wred[wd][3] = v4; wred[wd][4] = v8;
        }
        __syncthreads();
        if (t == 0) featA[bc] = (wred[0][0] + wred[1][0] + wred[2][0] + wred[3][0]) * (1.f / 4096.f);
        else if (t == 1) fm1[bc] = fmaxf(fmaxf(wred[0][1], wred[1][1]), fmaxf(wred[2][1], wred[3][1]));
        else if (t == 2) fm2[bc] = fmaxf(fmaxf(wred[0][2], wred[1][2]), fmaxf(wred[2][2], wred[3][2]));
        else if (t == 3) fm4[bc] = fmaxf(fmaxf(wred[0][3], wred[1][3]), fmaxf(wred[2][3], wred[3][3]));
        else if (t == 4) fm8[bc] = fmaxf(fmaxf(wred[0][4], wred[1][4]), fmaxf(wred[2][4], wred[3][4]));
    }
}

// ---------------------------------------------------------------------------
// K2: channel-gate MLP
// ---------------------------------------------------------------------------
__global__ __launch_bounds__(256) void k2_gate(
    const float* __restrict__ featA, const float* __restrict__ fm1,
    const float* __restrict__ fm2, const float* __restrict__ fm4, const float* __restrict__ fm8,
    const float* __restrict__ W1, const float* __restrict__ b1,
    const float* __restrict__ W2, const float* __restrict__ b2,
    float* __restrict__ g)
{
    __shared__ float sf[5][256];
    __shared__ float sh[5][16];
    __shared__ float hs[16];
    const int b = blockIdx.x, t = threadIdx.x;
    sf[0][t] = featA[b * 256 + t];
    sf[1][t] = fm1[b * 256 + t];
    sf[2][t] = fm2[b * 256 + t];
    sf[3][t] = fm4[b * 256 + t];
    sf[4][t] = fm8[b * 256 + t];
    __syncthreads();
    if (t < 80) {
        int f = t / 16, j = t % 16;
        float a = b1[j];
        for (int c = 0; c < 256; c++) a += sf[f][c] * W1[c * 16 + j];
        sh[f][j] = fmaxf(a, 0.f);
    }
    __syncthreads();
    if (t < 16) hs[t] = 4.f * sh[0][t] + sh[1][t] + sh[2][t] + sh[3][t] + sh[4][t];
    __syncthreads();
    float a = 8.f * b2[t];
    for (int j = 0; j < 16; j++) a += hs[j] * W2[j * 256 + t];
    g[b * 256 + t] = 1.f / (1.f + __expf(-a));
}

// ---------------------------------------------------------------------------
// K3: spatial-gate input. Grid 256: block = (b, 64-pixel chunk); 4 waves
// split the 256 channels; LDS cross-wave reduce.
// ---------------------------------------------------------------------------
__global__ __launch_bounds__(256) void k3_comp(
    const float* __restrict__ x, const float* __restrict__ bm2,
    const float* __restrict__ bm4, const float* __restrict__ bm8,
    const float* __restrict__ g, float* __restrict__ comp)
{
    __shared__ float sg[256];
    __shared__ float rmx[4][64];
    __shared__ float rsm[4][64];
    const int b = blockIdx.x >> 6;
    const int pix = ((blockIdx.x & 63) << 6) + (threadIdx.x & 63);
    const int wid = threadIdx.x >> 6;
    const int c0 = wid << 6;
    sg[threadIdx.x] = g[(b << 8) + threadIdx.x];
    __syncthreads();
    const int h = pix >> 6, w = pix & 63;
    const int i2 = ((h >> 1) << 5) + (w >> 1);
    const int i4 = ((h >> 2) << 4) + (w >> 2);
    const int i8 = ((h >> 3) << 3) + (w >> 3);
    const float* xb = x + ((size_t)b << 8) * 4096;
    const float* p2 = bm2 + ((size_t)b << 8) * 1024;
    const float* p4 = bm4 + ((size_t)b << 8) * 256;
    const float* p8 = bm8 + ((size_t)b << 8) * 64;
    float mx = -1e30f, sm = 0.f;
    for (int c = c0; c < c0 + 64; c++) {
        float gc = sg[c];
        float xv = xb[(size_t)c * 4096 + pix] * gc;
        float v2 = p2[c * 1024 + i2] * gc;
        float v4 = p4[c * 256 + i4] * gc;
        float v8 = p8[c * 64 + i8] * gc;
        mx = fmaxf(fmaxf(mx, xv), fmaxf(fmaxf(v2, v4), v8));
        sm += xv + v2 + v4 + v8;
    }
    rmx[wid][threadIdx.x & 63] = mx;
    rsm[wid][threadIdx.x & 63] = sm;
    __syncthreads();
    if (wid == 0) {
        int l = threadIdx.x;
        float m = fmaxf(fmaxf(rmx[0][l], rmx[1][l]), fmaxf(rmx[2][l], rmx[3][l]));
        float s = rsm[0][l] + rsm[1][l] + rsm[2][l] + rsm[3][l];
        comp[((size_t)b * 2) * 4096 + pix] = m;
        comp[((size_t)b * 2 + 1) * 4096 + pix] = s * (1.f / 1024.f);
    }
}

// ---------------------------------------------------------------------------
// K4: 7x7 conv (2->1, pad 3, no bias) + BN(eval) + sigmoid. Grid 256 x 64thr.
// ---------------------------------------------------------------------------
__global__ __launch_bounds__(64) void k4_spgate(
    const float* __restrict__ comp, const float* __restrict__ Wsp,
    const float* __restrict__ bn_g, const float* __restrict__ bn_b,
    const float* __restrict__ bn_m, const float* __restrict__ bn_v,
    float* __restrict__ spg)
{
    __shared__ float w[98];
    const int t = threadIdx.x;
    for (int i = t; i < 98; i += 64) w[i] = Wsp[i];
    __syncthreads();
    const int b = blockIdx.x >> 6;
    const int pix = ((blockIdx.x & 63) << 6) + t;
    const int h = pix >> 6, wx = pix & 63;
    const float* c0 = comp + (size_t)b * 2 * 4096;
    float acc = 0.f;
    for (int ci = 0; ci < 2; ci++)
        for (int kh = 0; kh < 7; kh++) {
            int hh = h + kh - 3;
            if (hh < 0 || hh >= 64) continue;
            for (int kw = 0; kw < 7; kw++) {
                int wwp = wx + kw - 3;
                if (wwp < 0 || wwp >= 64) continue;
                acc += c0[ci * 4096 + hh * 64 + wwp] * w[ci * 49 + kh * 7 + kw];
            }
        }
    float sc = rsqrtf(bn_v[0] + 1e-5f) * bn_g[0];
    float sp = (acc - bn_m[0]) * sc + bn_b[0];
    spg[b * 4096 + pix] = 1.f / (1.f + __expf(-sp));
}

// ---------------------------------------------------------------------------
// K_WCAST: bf16 copy of W[:,768:1024] rows (q|k|v order) -> WB[320][256]
// ---------------------------------------------------------------------------
__global__ __launch_bounds__(256) void k_wcast(
    const float* __restrict__ Wq, const float* __restrict__ Wk, const float* __restrict__ Wv,
    unsigned short* __restrict__ WB)
{
    const int o = blockIdx.x;
    const int t = threadIdx.x;
    const float* row = (o < 32) ? (Wq + (size_t)o * 1024)
                      : (o < 64) ? (Wk + (size_t)(o - 32) * 1024)
                                 : (Wv + (size_t)(o - 64) * 1024);
    WB[o * 256 + t] = f2bf(row[768 + t]);
}

// ---------------------------------------------------------------------------
// K_X2T: x2 fp32 [b][256 c][4096 n] -> x2T bf16 [b][4096 n][256 c]
// ---------------------------------------------------------------------------
__global__ __launch_bounds__(256) void k_x2t(
    const float* __restrict__ x2, unsigned short* __restrict__ x2T)
{
    __shared__ unsigned short T[64][72];
    const int b = blockIdx.z;
    const int cb = blockIdx.y * 64;
    const int nb = blockIdx.x * 64;
    const int t = threadIdx.x;
    #pragma unroll
    for (int r = 0; r < 16; r++) {
        int cl = (t >> 6) + 4 * r;
        int nl = t & 63;
        float v = x2[((size_t)(b * 256 + cb + cl)) * 4096 + nb + nl];
        T[nl][cl] = f2bf(v);
    }
    __syncthreads();
    #pragma unroll
    for (int pass = 0; pass < 4; pass++) {
        int nl = (t >> 4) + 16 * pass;
        int c4 = (t & 15) * 4;
        uint2 pk;
        pk.x = (unsigned)T[nl][c4] | ((unsigned)T[nl][c4 + 1] << 16);
        pk.y = (unsigned)T[nl][c4 + 2] | ((unsigned)T[nl][c4 + 3] << 16);
        *(uint2*)(x2T + ((size_t)(b * 4096 + nb + nl)) * 256 + cb + c4) = pk;
    }
}

// ---------------------------------------------------------------------------
// K6: fp32 projection GEMM for low-res P2/P4/P8 passes only.
// ---------------------------------------------------------------------------
__global__ __launch_bounds__(256) void k6_gemm(
    const float* __restrict__ Wq, const float* __restrict__ Wk, const float* __restrict__ Wv,
    int col_off, const float* __restrict__ src, int ns,
    float* __restrict__ outp)
{
    __shared__ float At[32][68];
    __shared__ float Bt[32][64];
    const int b = blockIdx.z;
    const int o_base = blockIdx.y * 64;
    const int n_base = blockIdx.x * 64;
    const int t = threadIdx.x;
    const int tn = t >> 4, tm = t & 15;
    const int lk = t & 31, lo8 = t >> 5;
    const int ln = t & 63, lk4 = t >> 6;
    float acc[4][4];
    #pragma unroll
    for (int i = 0; i < 4; i++)
        #pragma unroll
        for (int j = 0; j < 4; j++) acc[i][j] = 0.f;
    for (int k0 = 0; k0 < 256; k0 += 32) {
        __syncthreads();
        #pragma unroll
        for (int r = 0; r < 8; r++) {
            int o = o_base + lo8 + 8 * r;
            const float* wrow = (o < 32) ? (Wq + (size_t)o * 1024)
                              : (o < 64) ? (Wk + (size_t)(o - 32) * 1024)
                                         : (Wv + (size_t)(o - 64) * 1024);
            At[lk][lo8 + 8 * r] = wrow[col_off + k0 + lk];
        }
        #pragma unroll
        for (int r = 0; r < 8; r++)
            Bt[lk4 + 4 * r][ln] = src[((size_t)b * 256 + k0 + lk4 + 4 * r) * ns + n_base + ln];
        __syncthreads();
        #pragma unroll
        for (int kk = 0; kk < 32; kk++) {
            float4 a = *(const float4*)&At[kk][4 * tn];
            float4 bb = *(const float4*)&Bt[kk][4 * tm];
            acc[0][0] += a.x * bb.x; acc[0][1] += a.x * bb.y; acc[0][2] += a.x * bb.z; acc[0][3] += a.x * bb.w;
            acc[1][0] += a.y * bb.x; acc[1][1] += a.y * bb.y; acc[1][2] += a.y * bb.z; acc[1][3] += a.y * bb.w;
            acc[2][0] += a.z * bb.x; acc[2][1] += a.z * bb.y; acc[2][2] += a.z * bb.z; acc[2][3] += a.z * bb.w;
            acc[3][0] += a.w * bb.x; acc[3][1] += a.w * bb.y; acc[3][2] += a.w * bb.z; acc[3][3] += a.w * bb.w;
        }
    }
    #pragma unroll
    for (int i = 0; i < 4; i++)
        #pragma unroll
        for (int j = 0; j < 4; j++)
            outp[((size_t)b * 320 + o_base + 4 * tn + i) * ns + n_base + 4 * tm + j] = acc[i][j];
}

// ---------------------------------------------------------------------------
// K6M: full-res projection via bf16 MFMA. v writes go to chunked padded
// layout vC[b][n>>6][c][72] (m-in-chunk = n&63) for dense k7b staging.
// ---------------------------------------------------------------------------
__global__ __launch_bounds__(256) void k6m(
    const unsigned short* __restrict__ WB, const unsigned short* __restrict__ x2T,
    const float* __restrict__ bq, const float* __restrict__ bk, const float* __restrict__ bv,
    const float* __restrict__ P2, const float* __restrict__ P4, const float* __restrict__ P8,
    unsigned short* __restrict__ qT, unsigned short* __restrict__ kT,
    unsigned short* __restrict__ vC)
{
    const int b = blockIdx.z;
    const int obase = blockIdx.y * 64;
    const int nb = blockIdx.x * 128;
    const int t = threadIdx.x;
    const int w_ = t >> 6, lane = t & 63;
    const int quad = lane >> 4, l16 = lane & 15;
    const int nbase = nb + 32 * w_;
    f32x4 acc[4][2];
    #pragma unroll
    for (int ot = 0; ot < 4; ot++)
        #pragma unroll
        for (int nt = 0; nt < 2; nt++) { acc[ot][nt][0] = 0.f; acc[ot][nt][1] = 0.f; acc[ot][nt][2] = 0.f; acc[ot][nt][3] = 0.f; }
    const unsigned short* xb = x2T + ((size_t)b * 4096 + nbase) * 256;
    for (int k0 = 0; k0 < 256; k0 += 32) {
        FRAG af[4], bf[2];
        #pragma unroll
        for (int ot = 0; ot < 4; ot++)
            af[ot].u = *(const uint4*)(WB + (size_t)(obase + 16 * ot + l16) * 256 + k0 + quad * 8);
        #pragma unroll
        for (int nt = 0; nt < 2; nt++)
            bf[nt].u = *(const uint4*)(xb + (size_t)(16 * nt + l16) * 256 + k0 + quad * 8);
        #pragma unroll
        for (int ot = 0; ot < 4; ot++)
            #pragma unroll
            for (int nt = 0; nt < 2; nt++)
                acc[ot][nt] = __builtin_amdgcn_mfma_f32_16x16x32_bf16(af[ot].s, bf[nt].s, acc[ot][nt], 0, 0, 0);
    }
    #pragma unroll
    for (int ot = 0; ot < 4; ot++) {
        #pragma unroll
        for (int nt = 0; nt < 2; nt++) {
            int n = nbase + 16 * nt + l16;
            int h = n >> 6, wx = n & 63;
            int i2 = ((h >> 1) << 5) + (wx >> 1);
            int i4 = ((h >> 2) << 4) + (wx >> 2);
            int i8 = ((h >> 3) << 3) + (wx >> 3);
            float vals[4];
            #pragma unroll
            for (int r = 0; r < 4; r++) {
                int o = obase + 16 * ot + 4 * quad + r;
                float bias = (o < 32) ? bq[o] : (o < 64) ? bk[o - 32] : bv[o - 64];
                size_t ro = (size_t)b * 320 + o;
                vals[r] = acc[ot][nt][r] + bias
                        + P2[ro * 1024 + i2] + P4[ro * 256 + i4] + P8[ro * 64 + i8];
            }
            int o0 = obase + 16 * ot + 4 * quad;
            if (o0 < 64) {
                uint2 pk;
                pk.x = (unsigned)f2bf(vals[0]) | ((unsigned)f2bf(vals[1]) << 16);
                pk.y = (unsigned)f2bf(vals[2]) | ((unsigned)f2bf(vals[3]) << 16);
                if (o0 < 32)
                    *(uint2*)(qT + ((size_t)(b * 4096 + n)) * 32 + o0) = pk;
                else
                    *(uint2*)(kT + ((size_t)(b * 4096 + n)) * 32 + (o0 - 32)) = pk;
            } else {
                #pragma unroll
                for (int r = 0; r < 4; r++)
                    vC[(((size_t)b * 64 + (n >> 6)) * 256 + (o0 - 64 + r)) * 72 + (n & 63)] = f2bf(vals[r]);
            }
        }
    }
}

// ---------------------------------------------------------------------------
// K7A: softmax stats pass (unchanged from R7 — dense kT reads, fast).
// ---------------------------------------------------------------------------
__global__ __launch_bounds__(1024, 4) void k7a_stats(
    const unsigned short* __restrict__ qT, const unsigned short* __restrict__ kT,
    float* __restrict__ mout, float* __restrict__ ilout)
{
    __shared__ float sm[4][4][16], sl[4][4][16];   // [g][s][l16]
    const int b = blockIdx.x >> 6;
    const int qbase = (blockIdx.x & 63) << 6;
    const int t = threadIdx.x;
    const int wid = t >> 6, lane = t & 63;
    const int g_ = wid >> 2, s_ = wid & 3;
    const int quad = lane >> 4, l16 = lane & 15;

    FRAG qf;
    qf.u = *(const uint4*)(qT + ((size_t)(b * 4096 + qbase + 16 * g_ + l16)) * 32 + quad * 8);
    const unsigned short* kTb = kT + (size_t)b * 4096 * 32;

    float m_run = -1e30f, l_run = 0.f;
    for (int j = 0; j < 16; j++) {
        const int mo = (s_ << 10) + (j << 6);
        f32x4 e[4];
        #pragma unroll
        for (int mt = 0; mt < 4; mt++) {
            FRAG kf;
            kf.u = *(const uint4*)(kTb + (size_t)(mo + 16 * mt + l16) * 32 + quad * 8);
            f32x4 z; z[0] = 0.f; z[1] = 0.f; z[2] = 0.f; z[3] = 0.f;
            e[mt] = __builtin_amdgcn_mfma_f32_16x16x32_bf16(kf.s, qf.s, z, 0, 0, 0);
        }
        float pm = e[0][0];
        #pragma unroll
        for (int mt = 0; mt < 4; mt++)
            #pragma unroll
            for (int r = 0; r < 4; r++) pm = fmaxf(pm, e[mt][r]);
        float mnew = fmaxf(m_run, pm);
        float al = __expf(m_run - mnew);
        float ps = 0.f;
        #pragma unroll
        for (int mt = 0; mt < 4; mt++)
            #pragma unroll
            for (int r = 0; r < 4; r++) ps += __expf(e[mt][r] - mnew);
        l_run = l_run * al + ps;
        m_run = mnew;
    }
    #pragma unroll
    for (int o = 16; o < 64; o <<= 1) {
        float mo_ = __shfl_xor(m_run, o);
        float lo_ = __shfl_xor(l_run, o);
        float m2 = fmaxf(m_run, mo_);
        l_run = l_run * __expf(m_run - m2) + lo_ * __expf(mo_ - m2);
        m_run = m2;
    }
    if (quad == 0) { sm[g_][s_][l16] = m_run; sl[g_][s_][l16] = l_run; }
    __syncthreads();
    if (t < 64) {
        int g = t >> 4, l = t & 15;
        float m0 = sm[g][0][l], m1 = sm[g][1][l], m2 = sm[g][2][l], m3 = sm[g][3][l];
        float mx = fmaxf(fmaxf(m0, m1), fmaxf(m2, m3));
        float l_ = sl[g][0][l] * __expf(m0 - mx) + sl[g][1][l] * __expf(m1 - mx)
                 + sl[g][2][l] * __expf(m2 - mx) + sl[g][3][l] * __expf(m3 - mx);
        int n = qbase + 16 * g + l;
        mout[b * 4096 + n] = mx;
        ilout[b * 4096 + n] = 1.f / l_;
    }
}

// ---------------------------------------------------------------------------
// K7B v6: PV pass with LDS-STAGED V (the fix for scattered V loads).
// Block = (b, 64q), 512 thr / 8 waves = 4 c-stripes (cw) x 2 n-halves (gn).
// Per 64-key chunk: coalesced staging of vC chunk (36.9KB, padded rows) into
// VL; QK from dense kT overlaps staging; P (=exp(e-m), m precomputed) into
// shared PL; barrier; PV A-frags from VL, B-frags from PL (all <=2-way bank).
// Wave owns 64c x 32n; acc = 32 AGPRs; no combine (two-pass softmax).
// ---------------------------------------------------------------------------
__global__ __launch_bounds__(512) void k7b_attn(
    const unsigned short* __restrict__ qT, const unsigned short* __restrict__ kT,
    const unsigned short* __restrict__ vC, const float* __restrict__ mstat,
    const float* __restrict__ ilstat, const float* __restrict__ x2,
    const float* __restrict__ gamma, float* __restrict__ outp)
{
    __shared__ __align__(16) unsigned short VL[256 * 72];   // 36.9 KB V chunk [c][72m]
    __shared__ __align__(16) unsigned short PL[64][72];     // 9.2 KB P [n][72m]
    const int b = blockIdx.x >> 6;
    const int qbase = (blockIdx.x & 63) << 6;
    const int t = threadIdx.x;
    const int wid = t >> 6, lane = t & 63;
    const int cw = wid & 3, gn = wid >> 2;
    const int quad = lane >> 4, l16 = lane & 15;
    const int mt = wid & 3;                 // QK m-tile of this wave
    const int n0 = qbase + 32 * gn + l16;   // cols of this wave's two E/P rows
    const int n1 = n0 + 16;

    FRAG qf0, qf1;
    qf0.u = *(const uint4*)(qT + ((size_t)(b * 4096 + n0)) * 32 + quad * 8);
    qf1.u = *(const uint4*)(qT + ((size_t)(b * 4096 + n1)) * 32 + quad * 8);
    const float mN0 = mstat[b * 4096 + n0];
    const float mN1 = mstat[b * 4096 + n1];

    f32x4 acc[4][2];
    #pragma unroll
    for (int ct = 0; ct < 4; ct++)
        #pragma unroll
        for (int nt = 0; nt < 2; nt++) { acc[ct][nt][0] = 0.f; acc[ct][nt][1] = 0.f; acc[ct][nt][2] = 0.f; acc[ct][nt][3] = 0.f; }
    const unsigned short* kTb = kT + (size_t)b * 4096 * 32;
    const unsigned short* vCb = vC + (size_t)b * 64 * (256 * 72);

    for (int j = 0; j < 64; j++) {
        const int mo = j << 6;
        __syncthreads();                    // VL/PL free (prev iter reads done)
        // --- stage V chunk j: 36864 B = 2304 x 16B, coalesced both sides ---
        {
            const uint4* gsrc = (const uint4*)(vCb + (size_t)j * (256 * 72));
            uint4* ldst = (uint4*)VL;
            #pragma unroll
            for (int s = 0; s < 5; s++) {
                int idx = t + s * 512;
                if (idx < 2304) ldst[idx] = gsrc[idx];
            }
        }
        // --- QK (overlaps staging): E tiles (2gn, mt) and (2gn+1, mt) ---
        {
            FRAG kf;
            kf.u = *(const uint4*)(kTb + (size_t)(mo + 16 * mt + l16) * 32 + quad * 8);
            f32x4 z; z[0] = 0.f; z[1] = 0.f; z[2] = 0.f; z[3] = 0.f;
            f32x4 e0 = __builtin_amdgcn_mfma_f32_16x16x32_bf16(kf.s, qf0.s, z, 0, 0, 0);
            f32x4 e1 = __builtin_amdgcn_mfma_f32_16x16x32_bf16(kf.s, qf1.s, z, 0, 0, 0);
            union { float f; unsigned int u; } p0, p1, p2, p3;
            p0.f = __expf(e0[0] - mN0); p1.f = __expf(e0[1] - mN0);
            p2.f = __expf(e0[2] - mN0); p3.f = __expf(e0[3] - mN0);
            uint2 pk0;
            pk0.x = __builtin_amdgcn_perm(p1.u, p0.u, 0x07060302u);
            pk0.y = __builtin_amdgcn_perm(p3.u, p2.u, 0x07060302u);
            p0.f = __expf(e1[0] - mN1); p1.f = __expf(e1[1] - mN1);
            p2.f = __expf(e1[2] - mN1); p3.f = __expf(e1[3] - mN1);
            uint2 pk1;
            pk1.x = __builtin_amdgcn_perm(p1.u, p0.u, 0x07060302u);
            pk1.y = __builtin_amdgcn_perm(p3.u, p2.u, 0x07060302u);
            *(uint2*)&PL[32 * gn + l16][16 * mt + 4 * quad] = pk0;
            *(uint2*)&PL[32 * gn + 16 + l16][16 * mt + 4 * quad] = pk1;
        }
        __syncthreads();                    // VL staged + PL complete
        // --- PV: wave (cw, gn): O[64c x 32n] over this chunk's 64 keys ---
        #pragma unroll
        for (int kh = 0; kh < 2; kh++) {
            FRAG bp0, bp1, av[4];
            bp0.u = *(const uint4*)&PL[32 * gn + l16][32 * kh + quad * 8];
            bp1.u = *(const uint4*)&PL[32 * gn + 16 + l16][32 * kh + quad * 8];
            #pragma unroll
            for (int ct = 0; ct < 4; ct++)
                av[ct].u = *(const uint4*)&VL[(64 * cw + 16 * ct + l16) * 72 + 32 * kh + quad * 8];
            #pragma unroll
            for (int ct = 0; ct < 4; ct++) {
                acc[ct][0] = __builtin_amdgcn_mfma_f32_16x16x32_bf16(av[ct].s, bp0.s, acc[ct][0], 0, 0, 0);
                acc[ct][1] = __builtin_amdgcn_mfma_f32_16x16x32_bf16(av[ct].s, bp1.s, acc[ct][1], 0, 0, 0);
            }
        }
    }
    // --- epilogue: per-lane scale + residual, direct stores ---
    const float gm = gamma[0];
    const float sc0 = gm * ilstat[b * 4096 + n0];
    const float sc1 = gm * ilstat[b * 4096 + n1];
    #pragma unroll
    for (int ct = 0; ct < 4; ct++) {
        #pragma unroll
        for (int r = 0; r < 4; r++) {
            int c = 64 * cw + 16 * ct + 4 * quad + r;
            size_t idx0 = ((size_t)b * 256 + c) * 4096 + n0;
            size_t idx1 = ((size_t)b * 256 + c) * 4096 + n1;
            outp[idx0] = sc0 * acc[ct][0][r] + x2[idx0];
            outp[idx1] = sc1 * acc[ct][1][r] + x2[idx1];
        }
    }
}

// ---------------------------------------------------------------------------
extern "C" void kernel_launch(void* const* d_in, const int* in_sizes, int n_in,
                              void* d_out, int out_size, void* d_ws, size_t ws_size,
                              hipStream_t stream) {
    (void)in_sizes; (void)n_in; (void)out_size; (void)ws_size;
    const float* x    = (const float*)d_in[0];
    const float* W1   = (const float*)d_in[1];
    const float* b1   = (const float*)d_in[2];
    const float* W2   = (const float*)d_in[3];
    const float* b2   = (const float*)d_in[4];
    const float* Wq   = (const float*)d_in[5];
    const float* bq   = (const float*)d_in[6];
    const float* Wk   = (const float*)d_in[7];
    const float* bk   = (const float*)d_in[8];
    const float* Wv   = (const float*)d_in[9];
    const float* bv   = (const float*)d_in[10];
    const float* gam  = (const float*)d_in[11];
    const float* Wsp  = (const float*)d_in[12];
    const float* bn_g = (const float*)d_in[13];
    const float* bn_b = (const float*)d_in[14];
    const float* bn_m = (const float*)d_in[15];
    const float* bn_v = (const float*)d_in[16];

    float* ws = (float*)d_ws;
    float* bm2   = ws; ws += (size_t)4 * 256 * 1024;
    float* bm4   = ws; ws += (size_t)4 * 256 * 256;
    float* bm8   = ws; ws += (size_t)4 * 256 * 64;
    float* featA = ws; ws += 1024;
    float* fm1   = ws; ws += 1024;
    float* fm2   = ws; ws += 1024;
    float* fm4   = ws; ws += 1024;
    float* fm8   = ws; ws += 1024;
    float* g     = ws; ws += 1024;
    float* comp  = ws; ws += (size_t)4 * 2 * 4096;
    float* spg   = ws; ws += (size_t)4 * 4096;
    float* x2    = ws; ws += (size_t)4 * 256 * 4096;
    float* bm2b  = ws; ws += (size_t)4 * 256 * 1024;
    float* bm4b  = ws; ws += (size_t)4 * 256 * 256;
    float* bm8b  = ws; ws += (size_t)4 * 256 * 64;
    float* P2    = ws; ws += (size_t)4 * 320 * 1024;
    float* P4    = ws; ws += (size_t)4 * 320 * 256;
    float* P8    = ws; ws += (size_t)4 * 320 * 64;
    float* mstat = ws; ws += (size_t)4 * 4096;
    float* ilstat= ws; ws += (size_t)4 * 4096;
    unsigned short* qT  = (unsigned short*)ws; ws += (size_t)4 * 4096 * 32 / 2;
    unsigned short* kT  = (unsigned short*)ws; ws += (size_t)4 * 4096 * 32 / 2;
    unsigned short* vCp = (unsigned short*)ws; ws += (size_t)4 * 64 * 256 * 72 / 2;
    unsigned short* x2T = (unsigned short*)ws; ws += (size_t)4 * 4096 * 256 / 2;
    unsigned short* WB  = (unsigned short*)ws; ws += (size_t)320 * 256 / 2;

    // Weight cast (no deps)
    k_wcast<<<320, 256, 0, stream>>>(Wq, Wk, Wv, WB);
    // Stage 1: channel gate
    k_pyramid<<<1024, 256, 0, stream>>>(x, nullptr, nullptr, nullptr,
                                        bm2, bm4, bm8, featA, fm1, fm2, fm4, fm8, 0);
    k2_gate<<<4, 256, 0, stream>>>(featA, fm1, fm2, fm4, fm8, W1, b1, W2, b2, g);
    // Stage 2: spatial gate
    k3_comp<<<256, 256, 0, stream>>>(x, bm2, bm4, bm8, g, comp);
    k4_spgate<<<256, 64, 0, stream>>>(comp, Wsp, bn_g, bn_b, bn_m, bn_v, spg);
    k_pyramid<<<1024, 256, 0, stream>>>(x, g, spg, x2,
                                        bm2b, bm4b, bm8b,
                                        nullptr, nullptr, nullptr, nullptr, nullptr, 1);
    // x2 -> bf16 transposed [n][c]
    k_x2t<<<dim3(64, 4, 4), 256, 0, stream>>>(x2, x2T);
    // Stage 3: q/k/v projections, multiscale-decomposed
    k6_gemm<<<dim3(16, 5, 4), 256, 0, stream>>>(Wq, Wk, Wv, 0,   bm2b, 1024, P2);
    k6_gemm<<<dim3(4, 5, 4), 256, 0, stream>>>(Wq, Wk, Wv, 256, bm4b, 256,  P4);
    k6_gemm<<<dim3(1, 5, 4), 256, 0, stream>>>(Wq, Wk, Wv, 512, bm8b, 64,   P8);
    k6m<<<dim3(32, 5, 4), 256, 0, stream>>>(WB, x2T, bq, bk, bv, P2, P4, P8, qT, kT, vCp);
    // Two-pass attention: stats, then LDS-staged PV
    k7a_stats<<<256, 1024, 0, stream>>>(qT, kT, mstat, ilstat);
    k7b_attn<<<256, 512, 0, stream>>>(qT, kT, vCp, mstat, ilstat, x2, gam, (float*)d_out);
}

// Round 9
// 317.808 us; speedup vs baseline: 1.6456x; 1.0962x over previous
//
#include <hip/hip_runtime.h>
#include <math.h>

// Shapes (fixed): B=4, C=256, H=W=64, N=4096, 4C=1024, c8=32, r=16.

typedef float f32x4 __attribute__((ext_vector_type(4)));
typedef short s16x8 __attribute__((ext_vector_type(8)));
union FRAG { uint4 u; s16x8 s; };

__device__ __forceinline__ unsigned short f2bf(float f) {
    union { float f; unsigned int u; } v; v.f = f;
    unsigned int r = v.u + 0x7FFFu + ((v.u >> 16) & 1u);
    return (unsigned short)(r >> 16);
}

// ---------------------------------------------------------------------------
// K1/K5: per-(b,c) plane -> block-mean pyramid (+ feats in mode 0, x2 in mode 1)
// ---------------------------------------------------------------------------
__global__ __launch_bounds__(256) void k_pyramid(
    const float* __restrict__ xin, const float* __restrict__ gch,
    const float* __restrict__ spg, float* __restrict__ x2out,
    float* __restrict__ bm2, float* __restrict__ bm4, float* __restrict__ bm8,
    float* __restrict__ featA, float* __restrict__ fm1, float* __restrict__ fm2,
    float* __restrict__ fm4, float* __restrict__ fm8, int mode)
{
    __shared__ float sx[4096];
    __shared__ float s2[1024];
    __shared__ float s4[256];
    __shared__ float wred[4][8];
    const int bc = blockIdx.x;
    const int b = bc >> 8;
    const int t = threadIdx.x;
    const float* xp = xin + (size_t)bc * 4096;
    float gc = 1.f;
    if (mode == 1) gc = gch[bc];
    float sum = 0.f, mx = -1e30f;
    for (int r = 0; r < 4; r++) {
        int i4 = t + 256 * r;
        float4 v = ((const float4*)xp)[i4];
        if (mode == 1) {
            float4 sg = ((const float4*)(spg + (size_t)b * 4096))[i4];
            v.x *= gc * sg.x; v.y *= gc * sg.y; v.z *= gc * sg.z; v.w *= gc * sg.w;
            ((float4*)(x2out + (size_t)bc * 4096))[i4] = v;
        } else {
            sum += v.x + v.y + v.z + v.w;
            mx = fmaxf(mx, fmaxf(fmaxf(v.x, v.y), fmaxf(v.z, v.w)));
        }
        ((float4*)sx)[i4] = v;
    }
    __syncthreads();
    float mx2 = -1e30f;
    for (int r = 0; r < 4; r++) {
        int i = t + 256 * r;
        int r2 = i >> 5, c2 = i & 31;
        int p0 = 128 * r2 + 2 * c2;
        float v = 0.25f * (sx[p0] + sx[p0 + 1] + sx[p0 + 64] + sx[p0 + 65]);
        s2[i] = v;
        bm2[(size_t)bc * 1024 + i] = v;
        mx2 = fmaxf(mx2, v);
    }
    __syncthreads();
    float mx4;
    {
        int r4 = t >> 4, c4 = t & 15;
        int p0 = 64 * r4 + 2 * c4;
        float v = 0.25f * (s2[p0] + s2[p0 + 1] + s2[p0 + 32] + s2[p0 + 33]);
        s4[t] = v;
        bm4[(size_t)bc * 256 + t] = v;
        mx4 = v;
    }
    __syncthreads();
    float mx8 = -1e30f;
    if (t < 64) {
        int r8 = t >> 3, c8 = t & 7;
        int p0 = 32 * r8 + 2 * c8;
        float v = 0.25f * (s4[p0] + s4[p0 + 1] + s4[p0 + 16] + s4[p0 + 17]);
        bm8[(size_t)bc * 64 + t] = v;
        mx8 = v;
    }
    if (mode == 0) {
        float vs = sum, v1 = mx, v2 = mx2, v4 = mx4, v8 = mx8;
        #pragma unroll
        for (int o = 1; o < 64; o <<= 1) {
            vs += __shfl_xor(vs, o);
            v1 = fmaxf(v1, __shfl_xor(v1, o));
            v2 = fmaxf(v2, __shfl_xor(v2, o));
            v4 = fmaxf(v4, __shfl_xor(v4, o));
            v8 = fmaxf(v8, __shfl_xor(v8, o));
        }
        if ((t & 63) == 0) {
            int wd = t >> 6;
            wred[wd][0] = vs; wred[wd][1] = v1; wred[wd][2] = v2;
            wred[wd][3] = v4; wred[wd][4] = v8;
        }
        __syncthreads();
        if (t == 0) featA[bc] = (wred[0][0] + wred[1][0] + wred[2][0] + wred[3][0]) * (1.f / 4096.f);
        else if (t == 1) fm1[bc] = fmaxf(fmaxf(wred[0][1], wred[1][1]), fmaxf(wred[2][1], wred[3][1]));
        else if (t == 2) fm2[bc] = fmaxf(fmaxf(wred[0][2], wred[1][2]), fmaxf(wred[2][2], wred[3][2]));
        else if (t == 3) fm4[bc] = fmaxf(fmaxf(wred[0][3], wred[1][3]), fmaxf(wred[2][3], wred[3][3]));
        else if (t == 4) fm8[bc] = fmaxf(fmaxf(wred[0][4], wred[1][4]), fmaxf(wred[2][4], wred[3][4]));
    }
}

// ---------------------------------------------------------------------------
// K2: channel-gate MLP
// ---------------------------------------------------------------------------
__global__ __launch_bounds__(256) void k2_gate(
    const float* __restrict__ featA, const float* __restrict__ fm1,
    const float* __restrict__ fm2, const float* __restrict__ fm4, const float* __restrict__ fm8,
    const float* __restrict__ W1, const float* __restrict__ b1,
    const float* __restrict__ W2, const float* __restrict__ b2,
    float* __restrict__ g)
{
    __shared__ float sf[5][256];
    __shared__ float sh[5][16];
    __shared__ float hs[16];
    const int b = blockIdx.x, t = threadIdx.x;
    sf[0][t] = featA[b * 256 + t];
    sf[1][t] = fm1[b * 256 + t];
    sf[2][t] = fm2[b * 256 + t];
    sf[3][t] = fm4[b * 256 + t];
    sf[4][t] = fm8[b * 256 + t];
    __syncthreads();
    if (t < 80) {
        int f = t / 16, j = t % 16;
        float a = b1[j];
        for (int c = 0; c < 256; c++) a += sf[f][c] * W1[c * 16 + j];
        sh[f][j] = fmaxf(a, 0.f);
    }
    __syncthreads();
    if (t < 16) hs[t] = 4.f * sh[0][t] + sh[1][t] + sh[2][t] + sh[3][t] + sh[4][t];
    __syncthreads();
    float a = 8.f * b2[t];
    for (int j = 0; j < 16; j++) a += hs[j] * W2[j * 256 + t];
    g[b * 256 + t] = 1.f / (1.f + __expf(-a));
}

// ---------------------------------------------------------------------------
// K3: spatial-gate input. Grid 256: block = (b, 64-pixel chunk); 4 waves
// split the 256 channels; LDS cross-wave reduce.
// ---------------------------------------------------------------------------
__global__ __launch_bounds__(256) void k3_comp(
    const float* __restrict__ x, const float* __restrict__ bm2,
    const float* __restrict__ bm4, const float* __restrict__ bm8,
    const float* __restrict__ g, float* __restrict__ comp)
{
    __shared__ float sg[256];
    __shared__ float rmx[4][64];
    __shared__ float rsm[4][64];
    const int b = blockIdx.x >> 6;
    const int pix = ((blockIdx.x & 63) << 6) + (threadIdx.x & 63);
    const int wid = threadIdx.x >> 6;
    const int c0 = wid << 6;
    sg[threadIdx.x] = g[(b << 8) + threadIdx.x];
    __syncthreads();
    const int h = pix >> 6, w = pix & 63;
    const int i2 = ((h >> 1) << 5) + (w >> 1);
    const int i4 = ((h >> 2) << 4) + (w >> 2);
    const int i8 = ((h >> 3) << 3) + (w >> 3);
    const float* xb = x + ((size_t)b << 8) * 4096;
    const float* p2 = bm2 + ((size_t)b << 8) * 1024;
    const float* p4 = bm4 + ((size_t)b << 8) * 256;
    const float* p8 = bm8 + ((size_t)b << 8) * 64;
    float mx = -1e30f, sm = 0.f;
    for (int c = c0; c < c0 + 64; c++) {
        float gc = sg[c];
        float xv = xb[(size_t)c * 4096 + pix] * gc;
        float v2 = p2[c * 1024 + i2] * gc;
        float v4 = p4[c * 256 + i4] * gc;
        float v8 = p8[c * 64 + i8] * gc;
        mx = fmaxf(fmaxf(mx, xv), fmaxf(fmaxf(v2, v4), v8));
        sm += xv + v2 + v4 + v8;
    }
    rmx[wid][threadIdx.x & 63] = mx;
    rsm[wid][threadIdx.x & 63] = sm;
    __syncthreads();
    if (wid == 0) {
        int l = threadIdx.x;
        float m = fmaxf(fmaxf(rmx[0][l], rmx[1][l]), fmaxf(rmx[2][l], rmx[3][l]));
        float s = rsm[0][l] + rsm[1][l] + rsm[2][l] + rsm[3][l];
        comp[((size_t)b * 2) * 4096 + pix] = m;
        comp[((size_t)b * 2 + 1) * 4096 + pix] = s * (1.f / 1024.f);
    }
}

// ---------------------------------------------------------------------------
// K4: 7x7 conv (2->1, pad 3, no bias) + BN(eval) + sigmoid. Grid 256 x 64thr.
// ---------------------------------------------------------------------------
__global__ __launch_bounds__(64) void k4_spgate(
    const float* __restrict__ comp, const float* __restrict__ Wsp,
    const float* __restrict__ bn_g, const float* __restrict__ bn_b,
    const float* __restrict__ bn_m, const float* __restrict__ bn_v,
    float* __restrict__ spg)
{
    __shared__ float w[98];
    const int t = threadIdx.x;
    for (int i = t; i < 98; i += 64) w[i] = Wsp[i];
    __syncthreads();
    const int b = blockIdx.x >> 6;
    const int pix = ((blockIdx.x & 63) << 6) + t;
    const int h = pix >> 6, wx = pix & 63;
    const float* c0 = comp + (size_t)b * 2 * 4096;
    float acc = 0.f;
    for (int ci = 0; ci < 2; ci++)
        for (int kh = 0; kh < 7; kh++) {
            int hh = h + kh - 3;
            if (hh < 0 || hh >= 64) continue;
            for (int kw = 0; kw < 7; kw++) {
                int wwp = wx + kw - 3;
                if (wwp < 0 || wwp >= 64) continue;
                acc += c0[ci * 4096 + hh * 64 + wwp] * w[ci * 49 + kh * 7 + kw];
            }
        }
    float sc = rsqrtf(bn_v[0] + 1e-5f) * bn_g[0];
    float sp = (acc - bn_m[0]) * sc + bn_b[0];
    spg[b * 4096 + pix] = 1.f / (1.f + __expf(-sp));
}

// ---------------------------------------------------------------------------
// K_WCAST: bf16 copy of W[:,768:1024] rows (q|k|v order) -> WB[320][256]
// ---------------------------------------------------------------------------
__global__ __launch_bounds__(256) void k_wcast(
    const float* __restrict__ Wq, const float* __restrict__ Wk, const float* __restrict__ Wv,
    unsigned short* __restrict__ WB)
{
    const int o = blockIdx.x;
    const int t = threadIdx.x;
    const float* row = (o < 32) ? (Wq + (size_t)o * 1024)
                      : (o < 64) ? (Wk + (size_t)(o - 32) * 1024)
                                 : (Wv + (size_t)(o - 64) * 1024);
    WB[o * 256 + t] = f2bf(row[768 + t]);
}

// ---------------------------------------------------------------------------
// K_X2T: x2 fp32 [b][256 c][4096 n] -> x2T bf16 [b][4096 n][256 c]
// ---------------------------------------------------------------------------
__global__ __launch_bounds__(256) void k_x2t(
    const float* __restrict__ x2, unsigned short* __restrict__ x2T)
{
    __shared__ unsigned short T[64][72];
    const int b = blockIdx.z;
    const int cb = blockIdx.y * 64;
    const int nb = blockIdx.x * 64;
    const int t = threadIdx.x;
    #pragma unroll
    for (int r = 0; r < 16; r++) {
        int cl = (t >> 6) + 4 * r;
        int nl = t & 63;
        float v = x2[((size_t)(b * 256 + cb + cl)) * 4096 + nb + nl];
        T[nl][cl] = f2bf(v);
    }
    __syncthreads();
    #pragma unroll
    for (int pass = 0; pass < 4; pass++) {
        int nl = (t >> 4) + 16 * pass;
        int c4 = (t & 15) * 4;
        uint2 pk;
        pk.x = (unsigned)T[nl][c4] | ((unsigned)T[nl][c4 + 1] << 16);
        pk.y = (unsigned)T[nl][c4 + 2] | ((unsigned)T[nl][c4 + 3] << 16);
        *(uint2*)(x2T + ((size_t)(b * 4096 + nb + nl)) * 256 + cb + c4) = pk;
    }
}

// ---------------------------------------------------------------------------
// K6: fp32 projection GEMM for low-res P2/P4/P8 passes only.
// ---------------------------------------------------------------------------
__global__ __launch_bounds__(256) void k6_gemm(
    const float* __restrict__ Wq, const float* __restrict__ Wk, const float* __restrict__ Wv,
    int col_off, const float* __restrict__ src, int ns,
    float* __restrict__ outp)
{
    __shared__ float At[32][68];
    __shared__ float Bt[32][64];
    const int b = blockIdx.z;
    const int o_base = blockIdx.y * 64;
    const int n_base = blockIdx.x * 64;
    const int t = threadIdx.x;
    const int tn = t >> 4, tm = t & 15;
    const int lk = t & 31, lo8 = t >> 5;
    const int ln = t & 63, lk4 = t >> 6;
    float acc[4][4];
    #pragma unroll
    for (int i = 0; i < 4; i++)
        #pragma unroll
        for (int j = 0; j < 4; j++) acc[i][j] = 0.f;
    for (int k0 = 0; k0 < 256; k0 += 32) {
        __syncthreads();
        #pragma unroll
        for (int r = 0; r < 8; r++) {
            int o = o_base + lo8 + 8 * r;
            const float* wrow = (o < 32) ? (Wq + (size_t)o * 1024)
                              : (o < 64) ? (Wk + (size_t)(o - 32) * 1024)
                                         : (Wv + (size_t)(o - 64) * 1024);
            At[lk][lo8 + 8 * r] = wrow[col_off + k0 + lk];
        }
        #pragma unroll
        for (int r = 0; r < 8; r++)
            Bt[lk4 + 4 * r][ln] = src[((size_t)b * 256 + k0 + lk4 + 4 * r) * ns + n_base + ln];
        __syncthreads();
        #pragma unroll
        for (int kk = 0; kk < 32; kk++) {
            float4 a = *(const float4*)&At[kk][4 * tn];
            float4 bb = *(const float4*)&Bt[kk][4 * tm];
            acc[0][0] += a.x * bb.x; acc[0][1] += a.x * bb.y; acc[0][2] += a.x * bb.z; acc[0][3] += a.x * bb.w;
            acc[1][0] += a.y * bb.x; acc[1][1] += a.y * bb.y; acc[1][2] += a.y * bb.z; acc[1][3] += a.y * bb.w;
            acc[2][0] += a.z * bb.x; acc[2][1] += a.z * bb.y; acc[2][2] += a.z * bb.z; acc[2][3] += a.z * bb.w;
            acc[3][0] += a.w * bb.x; acc[3][1] += a.w * bb.y; acc[3][2] += a.w * bb.z; acc[3][3] += a.w * bb.w;
        }
    }
    #pragma unroll
    for (int i = 0; i < 4; i++)
        #pragma unroll
        for (int j = 0; j < 4; j++)
            outp[((size_t)b * 320 + o_base + 4 * tn + i) * ns + n_base + 4 * tm + j] = acc[i][j];
}

// ---------------------------------------------------------------------------
// K6M: full-res projection via bf16 MFMA. v writes go to chunked padded
// layout vC[b][n>>6][c][72] (m-in-chunk = n&63) for dense k7b staging.
// ---------------------------------------------------------------------------
__global__ __launch_bounds__(256) void k6m(
    const unsigned short* __restrict__ WB, const unsigned short* __restrict__ x2T,
    const float* __restrict__ bq, const float* __restrict__ bk, const float* __restrict__ bv,
    const float* __restrict__ P2, const float* __restrict__ P4, const float* __restrict__ P8,
    unsigned short* __restrict__ qT, unsigned short* __restrict__ kT,
    unsigned short* __restrict__ vC)
{
    const int b = blockIdx.z;
    const int obase = blockIdx.y * 64;
    const int nb = blockIdx.x * 128;
    const int t = threadIdx.x;
    const int w_ = t >> 6, lane = t & 63;
    const int quad = lane >> 4, l16 = lane & 15;
    const int nbase = nb + 32 * w_;
    f32x4 acc[4][2];
    #pragma unroll
    for (int ot = 0; ot < 4; ot++)
        #pragma unroll
        for (int nt = 0; nt < 2; nt++) { acc[ot][nt][0] = 0.f; acc[ot][nt][1] = 0.f; acc[ot][nt][2] = 0.f; acc[ot][nt][3] = 0.f; }
    const unsigned short* xb = x2T + ((size_t)b * 4096 + nbase) * 256;
    for (int k0 = 0; k0 < 256; k0 += 32) {
        FRAG af[4], bf[2];
        #pragma unroll
        for (int ot = 0; ot < 4; ot++)
            af[ot].u = *(const uint4*)(WB + (size_t)(obase + 16 * ot + l16) * 256 + k0 + quad * 8);
        #pragma unroll
        for (int nt = 0; nt < 2; nt++)
            bf[nt].u = *(const uint4*)(xb + (size_t)(16 * nt + l16) * 256 + k0 + quad * 8);
        #pragma unroll
        for (int ot = 0; ot < 4; ot++)
            #pragma unroll
            for (int nt = 0; nt < 2; nt++)
                acc[ot][nt] = __builtin_amdgcn_mfma_f32_16x16x32_bf16(af[ot].s, bf[nt].s, acc[ot][nt], 0, 0, 0);
    }
    #pragma unroll
    for (int ot = 0; ot < 4; ot++) {
        #pragma unroll
        for (int nt = 0; nt < 2; nt++) {
            int n = nbase + 16 * nt + l16;
            int h = n >> 6, wx = n & 63;
            int i2 = ((h >> 1) << 5) + (wx >> 1);
            int i4 = ((h >> 2) << 4) + (wx >> 2);
            int i8 = ((h >> 3) << 3) + (wx >> 3);
            float vals[4];
            #pragma unroll
            for (int r = 0; r < 4; r++) {
                int o = obase + 16 * ot + 4 * quad + r;
                float bias = (o < 32) ? bq[o] : (o < 64) ? bk[o - 32] : bv[o - 64];
                size_t ro = (size_t)b * 320 + o;
                vals[r] = acc[ot][nt][r] + bias
                        + P2[ro * 1024 + i2] + P4[ro * 256 + i4] + P8[ro * 64 + i8];
            }
            int o0 = obase + 16 * ot + 4 * quad;
            if (o0 < 64) {
                uint2 pk;
                pk.x = (unsigned)f2bf(vals[0]) | ((unsigned)f2bf(vals[1]) << 16);
                pk.y = (unsigned)f2bf(vals[2]) | ((unsigned)f2bf(vals[3]) << 16);
                if (o0 < 32)
                    *(uint2*)(qT + ((size_t)(b * 4096 + n)) * 32 + o0) = pk;
                else
                    *(uint2*)(kT + ((size_t)(b * 4096 + n)) * 32 + (o0 - 32)) = pk;
            } else {
                #pragma unroll
                for (int r = 0; r < 4; r++)
                    vC[(((size_t)b * 64 + (n >> 6)) * 256 + (o0 - 64 + r)) * 72 + (n & 63)] = f2bf(vals[r]);
            }
        }
    }
}

// ---------------------------------------------------------------------------
// K7A: softmax stats pass (unchanged — dense kT reads).
// ---------------------------------------------------------------------------
__global__ __launch_bounds__(1024, 4) void k7a_stats(
    const unsigned short* __restrict__ qT, const unsigned short* __restrict__ kT,
    float* __restrict__ mout, float* __restrict__ ilout)
{
    __shared__ float sm[4][4][16], sl[4][4][16];   // [g][s][l16]
    const int b = blockIdx.x >> 6;
    const int qbase = (blockIdx.x & 63) << 6;
    const int t = threadIdx.x;
    const int wid = t >> 6, lane = t & 63;
    const int g_ = wid >> 2, s_ = wid & 3;
    const int quad = lane >> 4, l16 = lane & 15;

    FRAG qf;
    qf.u = *(const uint4*)(qT + ((size_t)(b * 4096 + qbase + 16 * g_ + l16)) * 32 + quad * 8);
    const unsigned short* kTb = kT + (size_t)b * 4096 * 32;

    float m_run = -1e30f, l_run = 0.f;
    for (int j = 0; j < 16; j++) {
        const int mo = (s_ << 10) + (j << 6);
        f32x4 e[4];
        #pragma unroll
        for (int mt = 0; mt < 4; mt++) {
            FRAG kf;
            kf.u = *(const uint4*)(kTb + (size_t)(mo + 16 * mt + l16) * 32 + quad * 8);
            f32x4 z; z[0] = 0.f; z[1] = 0.f; z[2] = 0.f; z[3] = 0.f;
            e[mt] = __builtin_amdgcn_mfma_f32_16x16x32_bf16(kf.s, qf.s, z, 0, 0, 0);
        }
        float pm = e[0][0];
        #pragma unroll
        for (int mt = 0; mt < 4; mt++)
            #pragma unroll
            for (int r = 0; r < 4; r++) pm = fmaxf(pm, e[mt][r]);
        float mnew = fmaxf(m_run, pm);
        float al = __expf(m_run - mnew);
        float ps = 0.f;
        #pragma unroll
        for (int mt = 0; mt < 4; mt++)
            #pragma unroll
            for (int r = 0; r < 4; r++) ps += __expf(e[mt][r] - mnew);
        l_run = l_run * al + ps;
        m_run = mnew;
    }
    #pragma unroll
    for (int o = 16; o < 64; o <<= 1) {
        float mo_ = __shfl_xor(m_run, o);
        float lo_ = __shfl_xor(l_run, o);
        float m2 = fmaxf(m_run, mo_);
        l_run = l_run * __expf(m_run - m2) + lo_ * __expf(mo_ - m2);
        m_run = m2;
    }
    if (quad == 0) { sm[g_][s_][l16] = m_run; sl[g_][s_][l16] = l_run; }
    __syncthreads();
    if (t < 64) {
        int g = t >> 4, l = t & 15;
        float m0 = sm[g][0][l], m1 = sm[g][1][l], m2 = sm[g][2][l], m3 = sm[g][3][l];
        float mx = fmaxf(fmaxf(m0, m1), fmaxf(m2, m3));
        float l_ = sl[g][0][l] * __expf(m0 - mx) + sl[g][1][l] * __expf(m1 - mx)
                 + sl[g][2][l] * __expf(m2 - mx) + sl[g][3][l] * __expf(m3 - mx);
        int n = qbase + 16 * g + l;
        mout[b * 4096 + n] = mx;
        ilout[b * 4096 + n] = 1.f / l_;
    }
}

// ---------------------------------------------------------------------------
// K7B v7: software-pipelined LDS-staged PV.
// Iteration j: VL holds V(j), pk/vreg hold P(j)/V(j) staged in REGISTERS.
//   barrier -> commit vreg->VL, pk->PL (LDS writes only, no vmem wait)
//   barrier -> issue V(j+1) global prefetch + QK(j+1)+exp (overlaps PV)
//           -> PV(j) MFMAs from VL/PL.
// The global-load latency (the R8 per-iter ~1-3K cyc drain) now lands during
// the ~700-cyc PV phase. 2 barriers/iter but drains are lgkm-only.
// ---------------------------------------------------------------------------
__global__ __launch_bounds__(512) void k7b_attn(
    const unsigned short* __restrict__ qT, const unsigned short* __restrict__ kT,
    const unsigned short* __restrict__ vC, const float* __restrict__ mstat,
    const float* __restrict__ ilstat, const float* __restrict__ x2,
    const float* __restrict__ gamma, float* __restrict__ outp)
{
    __shared__ __align__(16) unsigned short VL[256 * 72];   // 36.9 KB V chunk [c][72m]
    __shared__ __align__(16) unsigned short PL[64][72];     // 9.2 KB P [n][72m]
    const int b = blockIdx.x >> 6;
    const int qbase = (blockIdx.x & 63) << 6;
    const int t = threadIdx.x;
    const int wid = t >> 6, lane = t & 63;
    const int cw = wid & 3, gn = wid >> 2;
    const int quad = lane >> 4, l16 = lane & 15;
    const int mt = wid & 3;                 // QK m-tile of this wave
    const int n0 = qbase + 32 * gn + l16;
    const int n1 = n0 + 16;

    FRAG qf0, qf1;
    qf0.u = *(const uint4*)(qT + ((size_t)(b * 4096 + n0)) * 32 + quad * 8);
    qf1.u = *(const uint4*)(qT + ((size_t)(b * 4096 + n1)) * 32 + quad * 8);
    const float mN0 = mstat[b * 4096 + n0];
    const float mN1 = mstat[b * 4096 + n1];

    f32x4 acc[4][2];
    #pragma unroll
    for (int ct = 0; ct < 4; ct++)
        #pragma unroll
        for (int nt = 0; nt < 2; nt++) { acc[ct][nt][0] = 0.f; acc[ct][nt][1] = 0.f; acc[ct][nt][2] = 0.f; acc[ct][nt][3] = 0.f; }
    const unsigned short* kTb = kT + (size_t)b * 4096 * 32;
    const uint4* vCb = (const uint4*)(vC + (size_t)b * 64 * (256 * 72));  // 2304 uint4/chunk

    uint4 vr0, vr1, vr2, vr3, vr4;
    uint2 pk0, pk1;
    vr4.x = vr4.y = vr4.z = vr4.w = 0u;

    // --- prologue: prefetch V(0) into regs; QK(0)+exp into pk ---
    {
        const uint4* gs = vCb;
        vr0 = gs[t]; vr1 = gs[t + 512]; vr2 = gs[t + 1024]; vr3 = gs[t + 1536];
        if (t < 256) vr4 = gs[t + 2048];
        FRAG kf;
        kf.u = *(const uint4*)(kTb + (size_t)(16 * mt + l16) * 32 + quad * 8);
        f32x4 z; z[0] = 0.f; z[1] = 0.f; z[2] = 0.f; z[3] = 0.f;
        f32x4 e0 = __builtin_amdgcn_mfma_f32_16x16x32_bf16(kf.s, qf0.s, z, 0, 0, 0);
        f32x4 e1 = __builtin_amdgcn_mfma_f32_16x16x32_bf16(kf.s, qf1.s, z, 0, 0, 0);
        union { float f; unsigned int u; } p0, p1, p2, p3;
        p0.f = __expf(e0[0] - mN0); p1.f = __expf(e0[1] - mN0);
        p2.f = __expf(e0[2] - mN0); p3.f = __expf(e0[3] - mN0);
        pk0.x = __builtin_amdgcn_perm(p1.u, p0.u, 0x07060302u);
        pk0.y = __builtin_amdgcn_perm(p3.u, p2.u, 0x07060302u);
        p0.f = __expf(e1[0] - mN1); p1.f = __expf(e1[1] - mN1);
        p2.f = __expf(e1[2] - mN1); p3.f = __expf(e1[3] - mN1);
        pk1.x = __builtin_amdgcn_perm(p1.u, p0.u, 0x07060302u);
        pk1.y = __builtin_amdgcn_perm(p3.u, p2.u, 0x07060302u);
    }

    for (int j = 0; j < 64; j++) {
        __syncthreads();                    // prior PV done reading VL/PL
        // --- commit staged chunk j to LDS (no vmem dependency here) ---
        {
            uint4* ldst = (uint4*)VL;
            ldst[t] = vr0; ldst[t + 512] = vr1; ldst[t + 1024] = vr2; ldst[t + 1536] = vr3;
            if (t < 256) ldst[t + 2048] = vr4;
            *(uint2*)&PL[32 * gn + l16][16 * mt + 4 * quad] = pk0;
            *(uint2*)&PL[32 * gn + 16 + l16][16 * mt + 4 * quad] = pk1;
        }
        __syncthreads();                    // VL/PL visible
        // --- prefetch V(j+1) + QK(j+1) (latency hides under PV below) ---
        if (j < 63) {
            const uint4* gs = vCb + (size_t)(j + 1) * 2304;
            vr0 = gs[t]; vr1 = gs[t + 512]; vr2 = gs[t + 1024]; vr3 = gs[t + 1536];
            if (t < 256) vr4 = gs[t + 2048];
            const int mo = (j + 1) << 6;
            FRAG kf;
            kf.u = *(const uint4*)(kTb + (size_t)(mo + 16 * mt + l16) * 32 + quad * 8);
            f32x4 z; z[0] = 0.f; z[1] = 0.f; z[2] = 0.f; z[3] = 0.f;
            f32x4 e0 = __builtin_amdgcn_mfma_f32_16x16x32_bf16(kf.s, qf0.s, z, 0, 0, 0);
            f32x4 e1 = __builtin_amdgcn_mfma_f32_16x16x32_bf16(kf.s, qf1.s, z, 0, 0, 0);
            union { float f; unsigned int u; } p0, p1, p2, p3;
            p0.f = __expf(e0[0] - mN0); p1.f = __expf(e0[1] - mN0);
            p2.f = __expf(e0[2] - mN0); p3.f = __expf(e0[3] - mN0);
            pk0.x = __builtin_amdgcn_perm(p1.u, p0.u, 0x07060302u);
            pk0.y = __builtin_amdgcn_perm(p3.u, p2.u, 0x07060302u);
            p0.f = __expf(e1[0] - mN1); p1.f = __expf(e1[1] - mN1);
            p2.f = __expf(e1[2] - mN1); p3.f = __expf(e1[3] - mN1);
            pk1.x = __builtin_amdgcn_perm(p1.u, p0.u, 0x07060302u);
            pk1.y = __builtin_amdgcn_perm(p3.u, p2.u, 0x07060302u);
        }
        // --- PV(j): wave (cw, gn): O[64c x 32n] over chunk j's 64 keys ---
        #pragma unroll
        for (int kh = 0; kh < 2; kh++) {
            FRAG bp0, bp1, av[4];
            bp0.u = *(const uint4*)&PL[32 * gn + l16][32 * kh + quad * 8];
            bp1.u = *(const uint4*)&PL[32 * gn + 16 + l16][32 * kh + quad * 8];
            #pragma unroll
            for (int ct = 0; ct < 4; ct++)
                av[ct].u = *(const uint4*)&VL[(64 * cw + 16 * ct + l16) * 72 + 32 * kh + quad * 8];
            #pragma unroll
            for (int ct = 0; ct < 4; ct++) {
                acc[ct][0] = __builtin_amdgcn_mfma_f32_16x16x32_bf16(av[ct].s, bp0.s, acc[ct][0], 0, 0, 0);
                acc[ct][1] = __builtin_amdgcn_mfma_f32_16x16x32_bf16(av[ct].s, bp1.s, acc[ct][1], 0, 0, 0);
            }
        }
    }
    // --- epilogue: per-lane scale + residual, direct stores ---
    const float gm = gamma[0];
    const float sc0 = gm * ilstat[b * 4096 + n0];
    const float sc1 = gm * ilstat[b * 4096 + n1];
    #pragma unroll
    for (int ct = 0; ct < 4; ct++) {
        #pragma unroll
        for (int r = 0; r < 4; r++) {
            int c = 64 * cw + 16 * ct + 4 * quad + r;
            size_t idx0 = ((size_t)b * 256 + c) * 4096 + n0;
            size_t idx1 = ((size_t)b * 256 + c) * 4096 + n1;
            outp[idx0] = sc0 * acc[ct][0][r] + x2[idx0];
            outp[idx1] = sc1 * acc[ct][1][r] + x2[idx1];
        }
    }
}

// ---------------------------------------------------------------------------
extern "C" void kernel_launch(void* const* d_in, const int* in_sizes, int n_in,
                              void* d_out, int out_size, void* d_ws, size_t ws_size,
                              hipStream_t stream) {
    (void)in_sizes; (void)n_in; (void)out_size; (void)ws_size;
    const float* x    = (const float*)d_in[0];
    const float* W1   = (const float*)d_in[1];
    const float* b1   = (const float*)d_in[2];
    const float* W2   = (const float*)d_in[3];
    const float* b2   = (const float*)d_in[4];
    const float* Wq   = (const float*)d_in[5];
    const float* bq   = (const float*)d_in[6];
    const float* Wk   = (const float*)d_in[7];
    const float* bk   = (const float*)d_in[8];
    const float* Wv   = (const float*)d_in[9];
    const float* bv   = (const float*)d_in[10];
    const float* gam  = (const float*)d_in[11];
    const float* Wsp  = (const float*)d_in[12];
    const float* bn_g = (const float*)d_in[13];
    const float* bn_b = (const float*)d_in[14];
    const float* bn_m = (const float*)d_in[15];
    const float* bn_v = (const float*)d_in[16];

    float* ws = (float*)d_ws;
    float* bm2   = ws; ws += (size_t)4 * 256 * 1024;
    float* bm4   = ws; ws += (size_t)4 * 256 * 256;
    float* bm8   = ws; ws += (size_t)4 * 256 * 64;
    float* featA = ws; ws += 1024;
    float* fm1   = ws; ws += 1024;
    float* fm2   = ws; ws += 1024;
    float* fm4   = ws; ws += 1024;
    float* fm8   = ws; ws += 1024;
    float* g     = ws; ws += 1024;
    float* comp  = ws; ws += (size_t)4 * 2 * 4096;
    float* spg   = ws; ws += (size_t)4 * 4096;
    float* x2    = ws; ws += (size_t)4 * 256 * 4096;
    float* bm2b  = ws; ws += (size_t)4 * 256 * 1024;
    float* bm4b  = ws; ws += (size_t)4 * 256 * 256;
    float* bm8b  = ws; ws += (size_t)4 * 256 * 64;
    float* P2    = ws; ws += (size_t)4 * 320 * 1024;
    float* P4    = ws; ws += (size_t)4 * 320 * 256;
    float* P8    = ws; ws += (size_t)4 * 320 * 64;
    float* mstat = ws; ws += (size_t)4 * 4096;
    float* ilstat= ws; ws += (size_t)4 * 4096;
    unsigned short* qT  = (unsigned short*)ws; ws += (size_t)4 * 4096 * 32 / 2;
    unsigned short* kT  = (unsigned short*)ws; ws += (size_t)4 * 4096 * 32 / 2;
    unsigned short* vCp = (unsigned short*)ws; ws += (size_t)4 * 64 * 256 * 72 / 2;
    unsigned short* x2T = (unsigned short*)ws; ws += (size_t)4 * 4096 * 256 / 2;
    unsigned short* WB  = (unsigned short*)ws; ws += (size_t)320 * 256 / 2;

    // Weight cast (no deps)
    k_wcast<<<320, 256, 0, stream>>>(Wq, Wk, Wv, WB);
    // Stage 1: channel gate
    k_pyramid<<<1024, 256, 0, stream>>>(x, nullptr, nullptr, nullptr,
                                        bm2, bm4, bm8, featA, fm1, fm2, fm4, fm8, 0);
    k2_gate<<<4, 256, 0, stream>>>(featA, fm1, fm2, fm4, fm8, W1, b1, W2, b2, g);
    // Stage 2: spatial gate
    k3_comp<<<256, 256, 0, stream>>>(x, bm2, bm4, bm8, g, comp);
    k4_spgate<<<256, 64, 0, stream>>>(comp, Wsp, bn_g, bn_b, bn_m, bn_v, spg);
    k_pyramid<<<1024, 256, 0, stream>>>(x, g, spg, x2,
                                        bm2b, bm4b, bm8b,
                                        nullptr, nullptr, nullptr, nullptr, nullptr, 1);
    // x2 -> bf16 transposed [n][c]
    k_x2t<<<dim3(64, 4, 4), 256, 0, stream>>>(x2, x2T);
    // Stage 3: q/k/v projections, multiscale-decomposed
    k6_gemm<<<dim3(16, 5, 4), 256, 0, stream>>>(Wq, Wk, Wv, 0,   bm2b, 1024, P2);
    k6_gemm<<<dim3(4, 5, 4), 256, 0, stream>>>(Wq, Wk, Wv, 256, bm4b, 256,  P4);
    k6_gemm<<<dim3(1, 5, 4), 256, 0, stream>>>(Wq, Wk, Wv, 512, bm8b, 64,   P8);
    k6m<<<dim3(32, 5, 4), 256, 0, stream>>>(WB, x2T, bq, bk, bv, P2, P4, P8, qT, kT, vCp);
    // Two-pass attention: stats, then pipelined LDS-staged PV
    k7a_stats<<<256, 1024, 0, stream>>>(qT, kT, mstat, ilstat);
    k7b_attn<<<256, 512, 0, stream>>>(qT, kT, vCp, mstat, ilstat, x2, gam, (float*)d_out);
}

// Round 10
// 307.098 us; speedup vs baseline: 1.7030x; 1.0349x over previous
//
#include <hip/hip_runtime.h>
#include <math.h>

// Shapes (fixed): B=4, C=256, H=W=64, N=4096, 4C=1024, c8=32, r=16.

typedef float f32x4 __attribute__((ext_vector_type(4)));
typedef short s16x8 __attribute__((ext_vector_type(8)));
union FRAG { uint4 u; s16x8 s; };

__device__ __forceinline__ unsigned short f2bf(float f) {
    union { float f; unsigned int u; } v; v.f = f;
    unsigned int r = v.u + 0x7FFFu + ((v.u >> 16) & 1u);
    return (unsigned short)(r >> 16);
}

// ---------------------------------------------------------------------------
// K1/K5: per-(b,c) plane -> block-mean pyramid (+ feats in mode 0, x2 in mode 1)
// ---------------------------------------------------------------------------
__global__ __launch_bounds__(256) void k_pyramid(
    const float* __restrict__ xin, const float* __restrict__ gch,
    const float* __restrict__ spg, float* __restrict__ x2out,
    float* __restrict__ bm2, float* __restrict__ bm4, float* __restrict__ bm8,
    float* __restrict__ featA, float* __restrict__ fm1, float* __restrict__ fm2,
    float* __restrict__ fm4, float* __restrict__ fm8, int mode)
{
    __shared__ float sx[4096];
    __shared__ float s2[1024];
    __shared__ float s4[256];
    __shared__ float wred[4][8];
    const int bc = blockIdx.x;
    const int b = bc >> 8;
    const int t = threadIdx.x;
    const float* xp = xin + (size_t)bc * 4096;
    float gc = 1.f;
    if (mode == 1) gc = gch[bc];
    float sum = 0.f, mx = -1e30f;
    for (int r = 0; r < 4; r++) {
        int i4 = t + 256 * r;
        float4 v = ((const float4*)xp)[i4];
        if (mode == 1) {
            float4 sg = ((const float4*)(spg + (size_t)b * 4096))[i4];
            v.x *= gc * sg.x; v.y *= gc * sg.y; v.z *= gc * sg.z; v.w *= gc * sg.w;
            ((float4*)(x2out + (size_t)bc * 4096))[i4] = v;
        } else {
            sum += v.x + v.y + v.z + v.w;
            mx = fmaxf(mx, fmaxf(fmaxf(v.x, v.y), fmaxf(v.z, v.w)));
        }
        ((float4*)sx)[i4] = v;
    }
    __syncthreads();
    float mx2 = -1e30f;
    for (int r = 0; r < 4; r++) {
        int i = t + 256 * r;
        int r2 = i >> 5, c2 = i & 31;
        int p0 = 128 * r2 + 2 * c2;
        float v = 0.25f * (sx[p0] + sx[p0 + 1] + sx[p0 + 64] + sx[p0 + 65]);
        s2[i] = v;
        bm2[(size_t)bc * 1024 + i] = v;
        mx2 = fmaxf(mx2, v);
    }
    __syncthreads();
    float mx4;
    {
        int r4 = t >> 4, c4 = t & 15;
        int p0 = 64 * r4 + 2 * c4;
        float v = 0.25f * (s2[p0] + s2[p0 + 1] + s2[p0 + 32] + s2[p0 + 33]);
        s4[t] = v;
        bm4[(size_t)bc * 256 + t] = v;
        mx4 = v;
    }
    __syncthreads();
    float mx8 = -1e30f;
    if (t < 64) {
        int r8 = t >> 3, c8 = t & 7;
        int p0 = 32 * r8 + 2 * c8;
        float v = 0.25f * (s4[p0] + s4[p0 + 1] + s4[p0 + 16] + s4[p0 + 17]);
        bm8[(size_t)bc * 64 + t] = v;
        mx8 = v;
    }
    if (mode == 0) {
        float vs = sum, v1 = mx, v2 = mx2, v4 = mx4, v8 = mx8;
        #pragma unroll
        for (int o = 1; o < 64; o <<= 1) {
            vs += __shfl_xor(vs, o);
            v1 = fmaxf(v1, __shfl_xor(v1, o));
            v2 = fmaxf(v2, __shfl_xor(v2, o));
            v4 = fmaxf(v4, __shfl_xor(v4, o));
            v8 = fmaxf(v8, __shfl_xor(v8, o));
        }
        if ((t & 63) == 0) {
            int wd = t >> 6;
            wred[wd][0] = vs; wred[wd][1] = v1; wred[wd][2] = v2;
            wred[wd][3] = v4; wred[wd][4] = v8;
        }
        __syncthreads();
        if (t == 0) featA[bc] = (wred[0][0] + wred[1][0] + wred[2][0] + wred[3][0]) * (1.f / 4096.f);
        else if (t == 1) fm1[bc] = fmaxf(fmaxf(wred[0][1], wred[1][1]), fmaxf(wred[2][1], wred[3][1]));
        else if (t == 2) fm2[bc] = fmaxf(fmaxf(wred[0][2], wred[1][2]), fmaxf(wred[2][2], wred[3][2]));
        else if (t == 3) fm4[bc] = fmaxf(fmaxf(wred[0][3], wred[1][3]), fmaxf(wred[2][3], wred[3][3]));
        else if (t == 4) fm8[bc] = fmaxf(fmaxf(wred[0][4], wred[1][4]), fmaxf(wred[2][4], wred[3][4]));
    }
}

// ---------------------------------------------------------------------------
// K2: channel-gate MLP
// ---------------------------------------------------------------------------
__global__ __launch_bounds__(256) void k2_gate(
    const float* __restrict__ featA, const float* __restrict__ fm1,
    const float* __restrict__ fm2, const float* __restrict__ fm4, const float* __restrict__ fm8,
    const float* __restrict__ W1, const float* __restrict__ b1,
    const float* __restrict__ W2, const float* __restrict__ b2,
    float* __restrict__ g)
{
    __shared__ float sf[5][256];
    __shared__ float sh[5][16];
    __shared__ float hs[16];
    const int b = blockIdx.x, t = threadIdx.x;
    sf[0][t] = featA[b * 256 + t];
    sf[1][t] = fm1[b * 256 + t];
    sf[2][t] = fm2[b * 256 + t];
    sf[3][t] = fm4[b * 256 + t];
    sf[4][t] = fm8[b * 256 + t];
    __syncthreads();
    if (t < 80) {
        int f = t / 16, j = t % 16;
        float a = b1[j];
        for (int c = 0; c < 256; c++) a += sf[f][c] * W1[c * 16 + j];
        sh[f][j] = fmaxf(a, 0.f);
    }
    __syncthreads();
    if (t < 16) hs[t] = 4.f * sh[0][t] + sh[1][t] + sh[2][t] + sh[3][t] + sh[4][t];
    __syncthreads();
    float a = 8.f * b2[t];
    for (int j = 0; j < 16; j++) a += hs[j] * W2[j * 256 + t];
    g[b * 256 + t] = 1.f / (1.f + __expf(-a));
}

// ---------------------------------------------------------------------------
// K3: spatial-gate input. Grid 256: block = (b, 64-pixel chunk); 4 waves
// split the 256 channels; LDS cross-wave reduce.
// ---------------------------------------------------------------------------
__global__ __launch_bounds__(256) void k3_comp(
    const float* __restrict__ x, const float* __restrict__ bm2,
    const float* __restrict__ bm4, const float* __restrict__ bm8,
    const float* __restrict__ g, float* __restrict__ comp)
{
    __shared__ float sg[256];
    __shared__ float rmx[4][64];
    __shared__ float rsm[4][64];
    const int b = blockIdx.x >> 6;
    const int pix = ((blockIdx.x & 63) << 6) + (threadIdx.x & 63);
    const int wid = threadIdx.x >> 6;
    const int c0 = wid << 6;
    sg[threadIdx.x] = g[(b << 8) + threadIdx.x];
    __syncthreads();
    const int h = pix >> 6, w = pix & 63;
    const int i2 = ((h >> 1) << 5) + (w >> 1);
    const int i4 = ((h >> 2) << 4) + (w >> 2);
    const int i8 = ((h >> 3) << 3) + (w >> 3);
    const float* xb = x + ((size_t)b << 8) * 4096;
    const float* p2 = bm2 + ((size_t)b << 8) * 1024;
    const float* p4 = bm4 + ((size_t)b << 8) * 256;
    const float* p8 = bm8 + ((size_t)b << 8) * 64;
    float mx = -1e30f, sm = 0.f;
    for (int c = c0; c < c0 + 64; c++) {
        float gc = sg[c];
        float xv = xb[(size_t)c * 4096 + pix] * gc;
        float v2 = p2[c * 1024 + i2] * gc;
        float v4 = p4[c * 256 + i4] * gc;
        float v8 = p8[c * 64 + i8] * gc;
        mx = fmaxf(fmaxf(mx, xv), fmaxf(fmaxf(v2, v4), v8));
        sm += xv + v2 + v4 + v8;
    }
    rmx[wid][threadIdx.x & 63] = mx;
    rsm[wid][threadIdx.x & 63] = sm;
    __syncthreads();
    if (wid == 0) {
        int l = threadIdx.x;
        float m = fmaxf(fmaxf(rmx[0][l], rmx[1][l]), fmaxf(rmx[2][l], rmx[3][l]));
        float s = rsm[0][l] + rsm[1][l] + rsm[2][l] + rsm[3][l];
        comp[((size_t)b * 2) * 4096 + pix] = m;
        comp[((size_t)b * 2 + 1) * 4096 + pix] = s * (1.f / 1024.f);
    }
}

// ---------------------------------------------------------------------------
// K4: 7x7 conv (2->1, pad 3, no bias) + BN(eval) + sigmoid. Grid 256 x 64thr.
// ---------------------------------------------------------------------------
__global__ __launch_bounds__(64) void k4_spgate(
    const float* __restrict__ comp, const float* __restrict__ Wsp,
    const float* __restrict__ bn_g, const float* __restrict__ bn_b,
    const float* __restrict__ bn_m, const float* __restrict__ bn_v,
    float* __restrict__ spg)
{
    __shared__ float w[98];
    const int t = threadIdx.x;
    for (int i = t; i < 98; i += 64) w[i] = Wsp[i];
    __syncthreads();
    const int b = blockIdx.x >> 6;
    const int pix = ((blockIdx.x & 63) << 6) + t;
    const int h = pix >> 6, wx = pix & 63;
    const float* c0 = comp + (size_t)b * 2 * 4096;
    float acc = 0.f;
    for (int ci = 0; ci < 2; ci++)
        for (int kh = 0; kh < 7; kh++) {
            int hh = h + kh - 3;
            if (hh < 0 || hh >= 64) continue;
            for (int kw = 0; kw < 7; kw++) {
                int wwp = wx + kw - 3;
                if (wwp < 0 || wwp >= 64) continue;
                acc += c0[ci * 4096 + hh * 64 + wwp] * w[ci * 49 + kh * 7 + kw];
            }
        }
    float sc = rsqrtf(bn_v[0] + 1e-5f) * bn_g[0];
    float sp = (acc - bn_m[0]) * sc + bn_b[0];
    spg[b * 4096 + pix] = 1.f / (1.f + __expf(-sp));
}

// ---------------------------------------------------------------------------
// K_WCAST: bf16 copy of W[:,768:1024] rows (q|k|v order) -> WB[320][256]
// ---------------------------------------------------------------------------
__global__ __launch_bounds__(256) void k_wcast(
    const float* __restrict__ Wq, const float* __restrict__ Wk, const float* __restrict__ Wv,
    unsigned short* __restrict__ WB)
{
    const int o = blockIdx.x;
    const int t = threadIdx.x;
    const float* row = (o < 32) ? (Wq + (size_t)o * 1024)
                      : (o < 64) ? (Wk + (size_t)(o - 32) * 1024)
                                 : (Wv + (size_t)(o - 64) * 1024);
    WB[o * 256 + t] = f2bf(row[768 + t]);
}

// ---------------------------------------------------------------------------
// K_X2T: x2 fp32 [b][256 c][4096 n] -> x2T bf16 [b][4096 n][256 c]
// ---------------------------------------------------------------------------
__global__ __launch_bounds__(256) void k_x2t(
    const float* __restrict__ x2, unsigned short* __restrict__ x2T)
{
    __shared__ unsigned short T[64][72];
    const int b = blockIdx.z;
    const int cb = blockIdx.y * 64;
    const int nb = blockIdx.x * 64;
    const int t = threadIdx.x;
    #pragma unroll
    for (int r = 0; r < 16; r++) {
        int cl = (t >> 6) + 4 * r;
        int nl = t & 63;
        float v = x2[((size_t)(b * 256 + cb + cl)) * 4096 + nb + nl];
        T[nl][cl] = f2bf(v);
    }
    __syncthreads();
    #pragma unroll
    for (int pass = 0; pass < 4; pass++) {
        int nl = (t >> 4) + 16 * pass;
        int c4 = (t & 15) * 4;
        uint2 pk;
        pk.x = (unsigned)T[nl][c4] | ((unsigned)T[nl][c4 + 1] << 16);
        pk.y = (unsigned)T[nl][c4 + 2] | ((unsigned)T[nl][c4 + 3] << 16);
        *(uint2*)(x2T + ((size_t)(b * 4096 + nb + nl)) * 256 + cb + c4) = pk;
    }
}

// ---------------------------------------------------------------------------
// K6: fp32 projection GEMM for low-res P2/P4/P8, all three scales in ONE
// launch: blockIdx.x 0..15 -> P2, 16..19 -> P4, 20 -> P8.
// ---------------------------------------------------------------------------
__global__ __launch_bounds__(256) void k6_gemm(
    const float* __restrict__ Wq, const float* __restrict__ Wk, const float* __restrict__ Wv,
    const float* __restrict__ bm2b, const float* __restrict__ bm4b, const float* __restrict__ bm8b,
    float* __restrict__ P2, float* __restrict__ P4, float* __restrict__ P8)
{
    __shared__ float At[32][68];
    __shared__ float Bt[32][64];
    const int bx = blockIdx.x;
    int col_off, ns, nb;
    const float* src;
    float* outp;
    if (bx < 16)      { col_off = 0;   src = bm2b; ns = 1024; outp = P2; nb = bx; }
    else if (bx < 20) { col_off = 256; src = bm4b; ns = 256;  outp = P4; nb = bx - 16; }
    else              { col_off = 512; src = bm8b; ns = 64;   outp = P8; nb = 0; }
    const int b = blockIdx.z;
    const int o_base = blockIdx.y * 64;
    const int n_base = nb * 64;
    const int t = threadIdx.x;
    const int tn = t >> 4, tm = t & 15;
    const int lk = t & 31, lo8 = t >> 5;
    const int ln = t & 63, lk4 = t >> 6;
    float acc[4][4];
    #pragma unroll
    for (int i = 0; i < 4; i++)
        #pragma unroll
        for (int j = 0; j < 4; j++) acc[i][j] = 0.f;
    for (int k0 = 0; k0 < 256; k0 += 32) {
        __syncthreads();
        #pragma unroll
        for (int r = 0; r < 8; r++) {
            int o = o_base + lo8 + 8 * r;
            const float* wrow = (o < 32) ? (Wq + (size_t)o * 1024)
                              : (o < 64) ? (Wk + (size_t)(o - 32) * 1024)
                                         : (Wv + (size_t)(o - 64) * 1024);
            At[lk][lo8 + 8 * r] = wrow[col_off + k0 + lk];
        }
        #pragma unroll
        for (int r = 0; r < 8; r++)
            Bt[lk4 + 4 * r][ln] = src[((size_t)b * 256 + k0 + lk4 + 4 * r) * ns + n_base + ln];
        __syncthreads();
        #pragma unroll
        for (int kk = 0; kk < 32; kk++) {
            float4 a = *(const float4*)&At[kk][4 * tn];
            float4 bb = *(const float4*)&Bt[kk][4 * tm];
            acc[0][0] += a.x * bb.x; acc[0][1] += a.x * bb.y; acc[0][2] += a.x * bb.z; acc[0][3] += a.x * bb.w;
            acc[1][0] += a.y * bb.x; acc[1][1] += a.y * bb.y; acc[1][2] += a.y * bb.z; acc[1][3] += a.y * bb.w;
            acc[2][0] += a.z * bb.x; acc[2][1] += a.z * bb.y; acc[2][2] += a.z * bb.z; acc[2][3] += a.z * bb.w;
            acc[3][0] += a.w * bb.x; acc[3][1] += a.w * bb.y; acc[3][2] += a.w * bb.z; acc[3][3] += a.w * bb.w;
        }
    }
    #pragma unroll
    for (int i = 0; i < 4; i++)
        #pragma unroll
        for (int j = 0; j < 4; j++)
            outp[((size_t)b * 320 + o_base + 4 * tn + i) * ns + n_base + 4 * tm + j] = acc[i][j];
}

// ---------------------------------------------------------------------------
// K6M: full-res projection via bf16 MFMA. v writes go to chunked padded
// layout vC[b][n>>6][c][72] (m-in-chunk = n&63) for dense k7b staging.
// ---------------------------------------------------------------------------
__global__ __launch_bounds__(256) void k6m(
    const unsigned short* __restrict__ WB, const unsigned short* __restrict__ x2T,
    const float* __restrict__ bq, const float* __restrict__ bk, const float* __restrict__ bv,
    const float* __restrict__ P2, const float* __restrict__ P4, const float* __restrict__ P8,
    unsigned short* __restrict__ qT, unsigned short* __restrict__ kT,
    unsigned short* __restrict__ vC)
{
    const int b = blockIdx.z;
    const int obase = blockIdx.y * 64;
    const int nb = blockIdx.x * 128;
    const int t = threadIdx.x;
    const int w_ = t >> 6, lane = t & 63;
    const int quad = lane >> 4, l16 = lane & 15;
    const int nbase = nb + 32 * w_;
    f32x4 acc[4][2];
    #pragma unroll
    for (int ot = 0; ot < 4; ot++)
        #pragma unroll
        for (int nt = 0; nt < 2; nt++) { acc[ot][nt][0] = 0.f; acc[ot][nt][1] = 0.f; acc[ot][nt][2] = 0.f; acc[ot][nt][3] = 0.f; }
    const unsigned short* xb = x2T + ((size_t)b * 4096 + nbase) * 256;
    for (int k0 = 0; k0 < 256; k0 += 32) {
        FRAG af[4], bf[2];
        #pragma unroll
        for (int ot = 0; ot < 4; ot++)
            af[ot].u = *(const uint4*)(WB + (size_t)(obase + 16 * ot + l16) * 256 + k0 + quad * 8);
        #pragma unroll
        for (int nt = 0; nt < 2; nt++)
            bf[nt].u = *(const uint4*)(xb + (size_t)(16 * nt + l16) * 256 + k0 + quad * 8);
        #pragma unroll
        for (int ot = 0; ot < 4; ot++)
            #pragma unroll
            for (int nt = 0; nt < 2; nt++)
                acc[ot][nt] = __builtin_amdgcn_mfma_f32_16x16x32_bf16(af[ot].s, bf[nt].s, acc[ot][nt], 0, 0, 0);
    }
    #pragma unroll
    for (int ot = 0; ot < 4; ot++) {
        #pragma unroll
        for (int nt = 0; nt < 2; nt++) {
            int n = nbase + 16 * nt + l16;
            int h = n >> 6, wx = n & 63;
            int i2 = ((h >> 1) << 5) + (wx >> 1);
            int i4 = ((h >> 2) << 4) + (wx >> 2);
            int i8 = ((h >> 3) << 3) + (wx >> 3);
            float vals[4];
            #pragma unroll
            for (int r = 0; r < 4; r++) {
                int o = obase + 16 * ot + 4 * quad + r;
                float bias = (o < 32) ? bq[o] : (o < 64) ? bk[o - 32] : bv[o - 64];
                size_t ro = (size_t)b * 320 + o;
                vals[r] = acc[ot][nt][r] + bias
                        + P2[ro * 1024 + i2] + P4[ro * 256 + i4] + P8[ro * 64 + i8];
            }
            int o0 = obase + 16 * ot + 4 * quad;
            if (o0 < 64) {
                uint2 pk;
                pk.x = (unsigned)f2bf(vals[0]) | ((unsigned)f2bf(vals[1]) << 16);
                pk.y = (unsigned)f2bf(vals[2]) | ((unsigned)f2bf(vals[3]) << 16);
                if (o0 < 32)
                    *(uint2*)(qT + ((size_t)(b * 4096 + n)) * 32 + o0) = pk;
                else
                    *(uint2*)(kT + ((size_t)(b * 4096 + n)) * 32 + (o0 - 32)) = pk;
            } else {
                #pragma unroll
                for (int r = 0; r < 4; r++)
                    vC[(((size_t)b * 64 + (n >> 6)) * 256 + (o0 - 64 + r)) * 72 + (n & 63)] = f2bf(vals[r]);
            }
        }
    }
}

// ---------------------------------------------------------------------------
// K7A: softmax stats pass (unchanged — dense kT reads).
// ---------------------------------------------------------------------------
__global__ __launch_bounds__(1024, 4) void k7a_stats(
    const unsigned short* __restrict__ qT, const unsigned short* __restrict__ kT,
    float* __restrict__ mout, float* __restrict__ ilout)
{
    __shared__ float sm[4][4][16], sl[4][4][16];   // [g][s][l16]
    const int b = blockIdx.x >> 6;
    const int qbase = (blockIdx.x & 63) << 6;
    const int t = threadIdx.x;
    const int wid = t >> 6, lane = t & 63;
    const int g_ = wid >> 2, s_ = wid & 3;
    const int quad = lane >> 4, l16 = lane & 15;

    FRAG qf;
    qf.u = *(const uint4*)(qT + ((size_t)(b * 4096 + qbase + 16 * g_ + l16)) * 32 + quad * 8);
    const unsigned short* kTb = kT + (size_t)b * 4096 * 32;

    float m_run = -1e30f, l_run = 0.f;
    for (int j = 0; j < 16; j++) {
        const int mo = (s_ << 10) + (j << 6);
        f32x4 e[4];
        #pragma unroll
        for (int mt = 0; mt < 4; mt++) {
            FRAG kf;
            kf.u = *(const uint4*)(kTb + (size_t)(mo + 16 * mt + l16) * 32 + quad * 8);
            f32x4 z; z[0] = 0.f; z[1] = 0.f; z[2] = 0.f; z[3] = 0.f;
            e[mt] = __builtin_amdgcn_mfma_f32_16x16x32_bf16(kf.s, qf.s, z, 0, 0, 0);
        }
        float pm = e[0][0];
        #pragma unroll
        for (int mt = 0; mt < 4; mt++)
            #pragma unroll
            for (int r = 0; r < 4; r++) pm = fmaxf(pm, e[mt][r]);
        float mnew = fmaxf(m_run, pm);
        float al = __expf(m_run - mnew);
        float ps = 0.f;
        #pragma unroll
        for (int mt = 0; mt < 4; mt++)
            #pragma unroll
            for (int r = 0; r < 4; r++) ps += __expf(e[mt][r] - mnew);
        l_run = l_run * al + ps;
        m_run = mnew;
    }
    #pragma unroll
    for (int o = 16; o < 64; o <<= 1) {
        float mo_ = __shfl_xor(m_run, o);
        float lo_ = __shfl_xor(l_run, o);
        float m2 = fmaxf(m_run, mo_);
        l_run = l_run * __expf(m_run - m2) + lo_ * __expf(mo_ - m2);
        m_run = m2;
    }
    if (quad == 0) { sm[g_][s_][l16] = m_run; sl[g_][s_][l16] = l_run; }
    __syncthreads();
    if (t < 64) {
        int g = t >> 4, l = t & 15;
        float m0 = sm[g][0][l], m1 = sm[g][1][l], m2 = sm[g][2][l], m3 = sm[g][3][l];
        float mx = fmaxf(fmaxf(m0, m1), fmaxf(m2, m3));
        float l_ = sl[g][0][l] * __expf(m0 - mx) + sl[g][1][l] * __expf(m1 - mx)
                 + sl[g][2][l] * __expf(m2 - mx) + sl[g][3][l] * __expf(m3 - mx);
        int n = qbase + 16 * g + l;
        mout[b * 4096 + n] = mx;
        ilout[b * 4096 + n] = 1.f / l_;
    }
}

// ---------------------------------------------------------------------------
// K7B v8: pipelined LDS-staged PV with 2x MFMA:LDS-read ratio.
// Block = (b, 64q), 512 thr / 8 waves. Wave wid: cw=wid&3 (64c stripe),
// khw=wid>>2 (32-key half); owns 64c x 64n over its key half ->
// acc[4][4] (64 AGPR; 2 waves/SIMD => 256-reg budget, no spill).
// QK: wave computes P-tiles (nt=wid&3, mt in {2khw, 2khw+1}).
// Per iter per wave: av[4]+bp[4] = 8 LDS reads -> 16 PV MFMA (ratio 2.0,
// was 1.33). Epilogue: one-time cross-khw combine via dedicated SB buffer.
// ---------------------------------------------------------------------------
__global__ __launch_bounds__(512) void k7b_attn(
    const unsigned short* __restrict__ qT, const unsigned short* __restrict__ kT,
    const unsigned short* __restrict__ vC, const float* __restrict__ mstat,
    const float* __restrict__ ilstat, const float* __restrict__ x2,
    const float* __restrict__ gamma, float* __restrict__ outp)
{
    __shared__ __align__(16) unsigned short VL[256 * 72];   // 36.9 KB V chunk [c][72m]
    __shared__ __align__(16) unsigned short PL[64][72];     // 9.2 KB P [n][72m]
    __shared__ float SB[128][68];                           // 34.8 KB combine buffer
    const int b = blockIdx.x >> 6;
    const int qbase = (blockIdx.x & 63) << 6;
    const int t = threadIdx.x;
    const int wid = t >> 6, lane = t & 63;
    const int cw = wid & 3, khw = wid >> 2;
    const int quad = lane >> 4, l16 = lane & 15;
    const int ntq = wid & 3;                // QK n-tile of this wave
    const int mt0 = 2 * khw, mt1 = 2 * khw + 1;
    const int nq = qbase + 16 * ntq + l16;  // column of this wave's P rows

    FRAG qf;
    qf.u = *(const uint4*)(qT + ((size_t)(b * 4096 + nq)) * 32 + quad * 8);
    const float mN = mstat[b * 4096 + nq];

    f32x4 acc[4][4];
    #pragma unroll
    for (int ct = 0; ct < 4; ct++)
        #pragma unroll
        for (int nt = 0; nt < 4; nt++) { acc[ct][nt][0] = 0.f; acc[ct][nt][1] = 0.f; acc[ct][nt][2] = 0.f; acc[ct][nt][3] = 0.f; }
    const unsigned short* kTb = kT + (size_t)b * 4096 * 32;
    const uint4* vCb = (const uint4*)(vC + (size_t)b * 64 * (256 * 72));  // 2304 uint4/chunk

    uint4 vr0, vr1, vr2, vr3, vr4;
    uint2 pkA, pkB;
    vr4.x = vr4.y = vr4.z = vr4.w = 0u;

    // --- prologue: prefetch V(0) into regs; QK(0)+exp into pkA/pkB ---
    {
        const uint4* gs = vCb;
        vr0 = gs[t]; vr1 = gs[t + 512]; vr2 = gs[t + 1024]; vr3 = gs[t + 1536];
        if (t < 256) vr4 = gs[t + 2048];
        FRAG kf0, kf1;
        kf0.u = *(const uint4*)(kTb + (size_t)(16 * mt0 + l16) * 32 + quad * 8);
        kf1.u = *(const uint4*)(kTb + (size_t)(16 * mt1 + l16) * 32 + quad * 8);
        f32x4 z; z[0] = 0.f; z[1] = 0.f; z[2] = 0.f; z[3] = 0.f;
        f32x4 e0 = __builtin_amdgcn_mfma_f32_16x16x32_bf16(kf0.s, qf.s, z, 0, 0, 0);
        f32x4 e1 = __builtin_amdgcn_mfma_f32_16x16x32_bf16(kf1.s, qf.s, z, 0, 0, 0);
        union { float f; unsigned int u; } p0, p1, p2, p3;
        p0.f = __expf(e0[0] - mN); p1.f = __expf(e0[1] - mN);
        p2.f = __expf(e0[2] - mN); p3.f = __expf(e0[3] - mN);
        pkA.x = __builtin_amdgcn_perm(p1.u, p0.u, 0x07060302u);
        pkA.y = __builtin_amdgcn_perm(p3.u, p2.u, 0x07060302u);
        p0.f = __expf(e1[0] - mN); p1.f = __expf(e1[1] - mN);
        p2.f = __expf(e1[2] - mN); p3.f = __expf(e1[3] - mN);
        pkB.x = __builtin_amdgcn_perm(p1.u, p0.u, 0x07060302u);
        pkB.y = __builtin_amdgcn_perm(p3.u, p2.u, 0x07060302u);
    }

    for (int j = 0; j < 64; j++) {
        __syncthreads();                    // prior PV done reading VL/PL
        // --- commit staged chunk j to LDS (no vmem dependency) ---
        {
            uint4* ldst = (uint4*)VL;
            ldst[t] = vr0; ldst[t + 512] = vr1; ldst[t + 1024] = vr2; ldst[t + 1536] = vr3;
            if (t < 256) ldst[t + 2048] = vr4;
            *(uint2*)&PL[16 * ntq + l16][16 * mt0 + 4 * quad] = pkA;
            *(uint2*)&PL[16 * ntq + l16][16 * mt1 + 4 * quad] = pkB;
        }
        __syncthreads();                    // VL/PL visible
        // --- prefetch V(j+1) + QK(j+1) (latency hides under PV below) ---
        if (j < 63) {
            const uint4* gs = vCb + (size_t)(j + 1) * 2304;
            vr0 = gs[t]; vr1 = gs[t + 512]; vr2 = gs[t + 1024]; vr3 = gs[t + 1536];
            if (t < 256) vr4 = gs[t + 2048];
            const int mo = (j + 1) << 6;
            FRAG kf0, kf1;
            kf0.u = *(const uint4*)(kTb + (size_t)(mo + 16 * mt0 + l16) * 32 + quad * 8);
            kf1.u = *(const uint4*)(kTb + (size_t)(mo + 16 * mt1 + l16) * 32 + quad * 8);
            f32x4 z; z[0] = 0.f; z[1] = 0.f; z[2] = 0.f; z[3] = 0.f;
            f32x4 e0 = __builtin_amdgcn_mfma_f32_16x16x32_bf16(kf0.s, qf.s, z, 0, 0, 0);
            f32x4 e1 = __builtin_amdgcn_mfma_f32_16x16x32_bf16(kf1.s, qf.s, z, 0, 0, 0);
            union { float f; unsigned int u; } p0, p1, p2, p3;
            p0.f = __expf(e0[0] - mN); p1.f = __expf(e0[1] - mN);
            p2.f = __expf(e0[2] - mN); p3.f = __expf(e0[3] - mN);
            pkA.x = __builtin_amdgcn_perm(p1.u, p0.u, 0x07060302u);
            pkA.y = __builtin_amdgcn_perm(p3.u, p2.u, 0x07060302u);
            p0.f = __expf(e1[0] - mN); p1.f = __expf(e1[1] - mN);
            p2.f = __expf(e1[2] - mN); p3.f = __expf(e1[3] - mN);
            pkB.x = __builtin_amdgcn_perm(p1.u, p0.u, 0x07060302u);
            pkB.y = __builtin_amdgcn_perm(p3.u, p2.u, 0x07060302u);
        }
        // --- PV(j): wave (cw,khw): 64c x 64n over keys [32khw, 32khw+32) ---
        {
            FRAG bp[4], av[4];
            #pragma unroll
            for (int nt = 0; nt < 4; nt++)
                bp[nt].u = *(const uint4*)&PL[16 * nt + l16][32 * khw + quad * 8];
            #pragma unroll
            for (int ct = 0; ct < 4; ct++)
                av[ct].u = *(const uint4*)&VL[(64 * cw + 16 * ct + l16) * 72 + 32 * khw + quad * 8];
            #pragma unroll
            for (int ct = 0; ct < 4; ct++)
                #pragma unroll
                for (int nt = 0; nt < 4; nt++)
                    acc[ct][nt] = __builtin_amdgcn_mfma_f32_16x16x32_bf16(av[ct].s, bp[nt].s, acc[ct][nt], 0, 0, 0);
        }
    }
    // --- epilogue: combine khw halves via SB, 2 c-stripe rounds ---
    const float gm = gamma[0];
    for (int s = 0; s < 2; s++) {
        __syncthreads();
        if (khw == 0 && (cw >> 1) == s) {
            #pragma unroll
            for (int ct = 0; ct < 4; ct++)
                #pragma unroll
                for (int nt = 0; nt < 4; nt++)
                    #pragma unroll
                    for (int r = 0; r < 4; r++)
                        SB[64 * (cw & 1) + 16 * ct + 4 * quad + r][16 * nt + l16] = acc[ct][nt][r];
        }
        __syncthreads();
        if (khw == 1 && (cw >> 1) == s) {
            #pragma unroll
            for (int ct = 0; ct < 4; ct++)
                #pragma unroll
                for (int nt = 0; nt < 4; nt++)
                    #pragma unroll
                    for (int r = 0; r < 4; r++)
                        SB[64 * (cw & 1) + 16 * ct + 4 * quad + r][16 * nt + l16] += acc[ct][nt][r];
        }
        __syncthreads();
        // cooperative store: 128c x 64n
        #pragma unroll
        for (int pass = 0; pass < 4; pass++) {
            int cl = (t >> 4) + 32 * pass;
            int n4 = (t & 15) * 4;
            float4 vv = *(float4*)&SB[cl][n4];
            float4 il4 = *(const float4*)(ilstat + (size_t)b * 4096 + qbase + n4);
            size_t idx = ((size_t)(b * 256 + 128 * s + cl)) * 4096 + qbase + n4;
            float4 xv = *(const float4*)(x2 + idx);
            float4 ov;
            ov.x = gm * vv.x * il4.x + xv.x;
            ov.y = gm * vv.y * il4.y + xv.y;
            ov.z = gm * vv.z * il4.z + xv.z;
            ov.w = gm * vv.w * il4.w + xv.w;
            *(float4*)(outp + idx) = ov;
        }
    }
}

// ---------------------------------------------------------------------------
extern "C" void kernel_launch(void* const* d_in, const int* in_sizes, int n_in,
                              void* d_out, int out_size, void* d_ws, size_t ws_size,
                              hipStream_t stream) {
    (void)in_sizes; (void)n_in; (void)out_size; (void)ws_size;
    const float* x    = (const float*)d_in[0];
    const float* W1   = (const float*)d_in[1];
    const float* b1   = (const float*)d_in[2];
    const float* W2   = (const float*)d_in[3];
    const float* b2   = (const float*)d_in[4];
    const float* Wq   = (const float*)d_in[5];
    const float* bq   = (const float*)d_in[6];
    const float* Wk   = (const float*)d_in[7];
    const float* bk   = (const float*)d_in[8];
    const float* Wv   = (const float*)d_in[9];
    const float* bv   = (const float*)d_in[10];
    const float* gam  = (const float*)d_in[11];
    const float* Wsp  = (const float*)d_in[12];
    const float* bn_g = (const float*)d_in[13];
    const float* bn_b = (const float*)d_in[14];
    const float* bn_m = (const float*)d_in[15];
    const float* bn_v = (const float*)d_in[16];

    float* ws = (float*)d_ws;
    float* bm2   = ws; ws += (size_t)4 * 256 * 1024;
    float* bm4   = ws; ws += (size_t)4 * 256 * 256;
    float* bm8   = ws; ws += (size_t)4 * 256 * 64;
    float* featA = ws; ws += 1024;
    float* fm1   = ws; ws += 1024;
    float* fm2   = ws; ws += 1024;
    float* fm4   = ws; ws += 1024;
    float* fm8   = ws; ws += 1024;
    float* g     = ws; ws += 1024;
    float* comp  = ws; ws += (size_t)4 * 2 * 4096;
    float* spg   = ws; ws += (size_t)4 * 4096;
    float* x2    = ws; ws += (size_t)4 * 256 * 4096;
    float* bm2b  = ws; ws += (size_t)4 * 256 * 1024;
    float* bm4b  = ws; ws += (size_t)4 * 256 * 256;
    float* bm8b  = ws; ws += (size_t)4 * 256 * 64;
    float* P2    = ws; ws += (size_t)4 * 320 * 1024;
    float* P4    = ws; ws += (size_t)4 * 320 * 256;
    float* P8    = ws; ws += (size_t)4 * 320 * 64;
    float* mstat = ws; ws += (size_t)4 * 4096;
    float* ilstat= ws; ws += (size_t)4 * 4096;
    unsigned short* qT  = (unsigned short*)ws; ws += (size_t)4 * 4096 * 32 / 2;
    unsigned short* kT  = (unsigned short*)ws; ws += (size_t)4 * 4096 * 32 / 2;
    unsigned short* vCp = (unsigned short*)ws; ws += (size_t)4 * 64 * 256 * 72 / 2;
    unsigned short* x2T = (unsigned short*)ws; ws += (size_t)4 * 4096 * 256 / 2;
    unsigned short* WB  = (unsigned short*)ws; ws += (size_t)320 * 256 / 2;

    // Weight cast (no deps)
    k_wcast<<<320, 256, 0, stream>>>(Wq, Wk, Wv, WB);
    // Stage 1: channel gate
    k_pyramid<<<1024, 256, 0, stream>>>(x, nullptr, nullptr, nullptr,
                                        bm2, bm4, bm8, featA, fm1, fm2, fm4, fm8, 0);
    k2_gate<<<4, 256, 0, stream>>>(featA, fm1, fm2, fm4, fm8, W1, b1, W2, b2, g);
    // Stage 2: spatial gate
    k3_comp<<<256, 256, 0, stream>>>(x, bm2, bm4, bm8, g, comp);
    k4_spgate<<<256, 64, 0, stream>>>(comp, Wsp, bn_g, bn_b, bn_m, bn_v, spg);
    k_pyramid<<<1024, 256, 0, stream>>>(x, g, spg, x2,
                                        bm2b, bm4b, bm8b,
                                        nullptr, nullptr, nullptr, nullptr, nullptr, 1);
    // x2 -> bf16 transposed [n][c]
    k_x2t<<<dim3(64, 4, 4), 256, 0, stream>>>(x2, x2T);
    // Stage 3: q/k/v projections, multiscale-decomposed (single low-res launch)
    k6_gemm<<<dim3(21, 5, 4), 256, 0, stream>>>(Wq, Wk, Wv, bm2b, bm4b, bm8b, P2, P4, P8);
    k6m<<<dim3(32, 5, 4), 256, 0, stream>>>(WB, x2T, bq, bk, bv, P2, P4, P8, qT, kT, vCp);
    // Two-pass attention: stats, then pipelined LDS-staged PV
    k7a_stats<<<256, 1024, 0, stream>>>(qT, kT, mstat, ilstat);
    k7b_attn<<<256, 512, 0, stream>>>(qT, kT, vCp, mstat, ilstat, x2, gam, (float*)d_out);
}